// Round 11
// baseline (389.386 us; speedup 1.0000x reference)
//
#include <hip/hip_runtime.h>

typedef unsigned short u16;
typedef unsigned int u32;
typedef __bf16 bf16x8 __attribute__((ext_vector_type(8)));
typedef float f32x4 __attribute__((ext_vector_type(4)));
typedef float f32x16 __attribute__((ext_vector_type(16)));

#define NCH 34   // cross-attn split-K chunks (m-chunk = 160, 5 steps of 32)
#define NSTEP 5
#define LOG2E 1.4426950408889634f

__device__ __forceinline__ u16 f2b(float f) {
  u32 u = __float_as_uint(f);
  u32 r = (u + 0x7fffu + ((u >> 16) & 1u)) >> 16;   // RNE, inputs finite
  return (u16)r;
}
__device__ __forceinline__ float b2f(u16 h) {
  return __uint_as_float(((u32)h) << 16);
}
__device__ __forceinline__ bf16x8 zero8() {
  union { uint4 u; bf16x8 v; } z; z.u = make_uint4(0u, 0u, 0u, 0u); return z.v;
}
__device__ __forceinline__ u32 cvtpk(float lo, float hi) {
  u32 r;
  asm("v_cvt_pk_bf16_f32 %0, %1, %2" : "=v"(r) : "v"(lo), "v"(hi));
  return r;
}

// ================= PREP: weight cvt + Wf pack + bias pack + bias repack =======
struct Seg { const float* in; u16* out; int n4; };
struct PrepArgs {
  Seg seg[7];
  const float *k_w, *v_w, *k_b, *v_b, *pbias;
  u16 *Wf;
  uint4 *biasT5;
  float *kvB;
};

// grid: [0,1472) f2b | [1472,1536) Wf pack | [1536,1538) kv bias | [1538,4258) bias repack
__global__ __launch_bounds__(256)
void prep_kernel(PrepArgs a)
{
  __shared__ float S[100][34];
  const int bx = blockIdx.x, tid = threadIdx.x;
  if (bx < 1472) {
    int bxr = bx;
#pragma unroll
    for (int k = 0; k < 7; ++k) {
      const int nb = a.seg[k].n4 >> 8;
      if (bxr < nb) {
        const int i = bxr * 256 + tid;
        const float4 f = *(const float4*)(a.seg[k].in + (size_t)i * 4);
        uint2 pk; pk.x = cvtpk(f.x, f.y); pk.y = cvtpk(f.z, f.w);
        *(uint2*)(a.seg[k].out + (size_t)i * 4) = pk;
        return;
      }
      bxr -= nb;
    }
    return;
  } else if (bx < 1536) {
    // fragment-major pack: Wf[((gI*8+ks)*4+nt)*512 + lane*8 + j]
    const int i = bx - 1472, gI = i >> 3, ks = i & 7;
    const int nt = tid >> 6, lane = tid & 63, lr = lane & 15, g = lane >> 4;
    const float* src = (gI < 4 ? a.k_w + (size_t)(gI * 64 + nt * 16 + lr) * 256
                               : a.v_w + (size_t)((gI - 4) * 64 + nt * 16 + lr) * 256)
                       + ks * 32 + g * 8;
    const float4 f0 = *(const float4*)src;
    const float4 f1 = *(const float4*)(src + 4);
    uint4 pk;
    pk.x = cvtpk(f0.x, f0.y); pk.y = cvtpk(f0.z, f0.w);
    pk.z = cvtpk(f1.x, f1.y); pk.w = cvtpk(f1.z, f1.w);
    *(uint4*)(a.Wf + (size_t)((gI * 8 + ks) * 4 + nt) * 512 + lane * 8) = pk;
  } else if (bx < 1538) {
    const int i = (bx - 1536) * 256 + tid;
    a.kvB[i] = (i < 256) ? a.k_b[i] : a.v_b[i - 256];
  } else {
    // bias repack for swapped-QK (log2e-scaled): biasT5[bt][qb][half][lane] uint4
    // lane (q = qb*32 + lane&31, hh = lane>>5) holds 16 bf16 in S-reg order:
    //   reg = half*8+i -> m = (reg&3) + 8*(reg>>2) + 4*hh
    const int bt = bx - 1538;          // 0..2719
    const int b = bt / 170, sg = bt - b * 170;
    const int m0 = sg * 32;
    for (int idx = tid; idx < 800; idx += 256) {
      const int q = idx >> 3, seg = idx & 7;
      const float4 v = *(const float4*)(a.pbias + (size_t)(b * 100 + q) * 5440 + m0 + seg * 4);
      S[q][seg * 4 + 0] = v.x; S[q][seg * 4 + 1] = v.y;
      S[q][seg * 4 + 2] = v.z; S[q][seg * 4 + 3] = v.w;
    }
    __syncthreads();
#pragma unroll
    for (int pass = 0; pass < 2; ++pass) {
      const int idx = pass * 256 + tid;
      const int qb = idx >> 7, r2 = idx & 127;
      const int half = r2 >> 6, lane = r2 & 63;
      const int q = qb * 32 + (lane & 31), hh = lane >> 5;
      u16 hv[8];
#pragma unroll
      for (int i = 0; i < 8; ++i) {
        const int reg = half * 8 + i;
        const int m = (reg & 3) + 8 * (reg >> 2) + 4 * hh;
        hv[i] = (q < 100) ? f2b(S[q][m] * LOG2E) : (u16)0;
      }
      uint4 pk;
      pk.x = (u32)hv[0] | ((u32)hv[1] << 16);
      pk.y = (u32)hv[2] | ((u32)hv[3] << 16);
      pk.z = (u32)hv[4] | ((u32)hv[5] << 16);
      pk.w = (u32)hv[6] | ((u32)hv[7] << 16);
      a.biasT5[((size_t)(bt * 4 + qb)) * 128 + half * 64 + lane] = pk;
    }
  }
}

// ---------------- LN staging into swizzled bf16 LDS tile [ROWS][256] ----------
template<int ROWS>
__device__ __forceinline__ void ln_stage(const float* __restrict__ x, int row0,
    const float* __restrict__ w, const float* __restrict__ b,
    const float* __restrict__ pos, u16* As)
{
  const int tid = threadIdx.x, lane = tid & 63, wid = tid >> 6;
  const float4 wv = *(const float4*)(w + lane * 4);
  const float4 bv = *(const float4*)(b + lane * 4);
#pragma unroll
  for (int rr = 0; rr < ROWS / 4; ++rr) {
    const int rl = wid * (ROWS / 4) + rr;
    const size_t o = (size_t)(row0 + rl) * 256 + lane * 4;
    const float4 v = *(const float4*)(x + o);
    float s = v.x + v.y + v.z + v.w;
#pragma unroll
    for (int m = 1; m < 64; m <<= 1) s += __shfl_xor(s, m);
    const float mean = s * (1.f / 256.f);
    const float d0 = v.x - mean, d1 = v.y - mean, d2 = v.z - mean, d3 = v.w - mean;
    float ss = d0 * d0 + d1 * d1 + d2 * d2 + d3 * d3;
#pragma unroll
    for (int m = 1; m < 64; m <<= 1) ss += __shfl_xor(ss, m);
    const float rs = rsqrtf(ss * (1.f / 256.f) + 1e-5f);
    float y0 = d0 * rs * wv.x + bv.x;
    float y1 = d1 * rs * wv.y + bv.y;
    float y2 = d2 * rs * wv.z + bv.z;
    float y3 = d3 * rs * wv.w + bv.w;
    if (pos) {
      const float4 pv = *(const float4*)(pos + o);
      y0 += pv.x; y1 += pv.y; y2 += pv.z; y3 += pv.w;
    }
    uint2 pk; pk.x = cvtpk(y0, y1); pk.y = cvtpk(y2, y3);
    const int byte = (rl * 512 + lane * 8) ^ ((rl & 7) << 4);
    *(uint2*)((char*)As + byte) = pk;
  }
}

// 16x128 GEMM loop reading A from full-K swizzled LDS; W staged per k0.
__device__ __forceinline__ void gemm16x128(const u16* As, const u16* __restrict__ W,
                                           u16 (*Ws)[40], f32x4 acc[2])
{
  const int tid = threadIdx.x, lane = tid & 63, wid = tid >> 6;
  const int g = lane >> 4, lr = lane & 15;
  for (int k0 = 0; k0 < 256; k0 += 32) {
    for (int cid = tid; cid < 512; cid += 256) {
      const int r = cid >> 2, cg = (cid & 3) * 8;
      *(uint4*)&Ws[r][cg] = *(const uint4*)(W + (size_t)r * 256 + k0 + cg);
    }
    __syncthreads();
    const int abyte = (lr * 512 + k0 * 2 + g * 16) ^ ((lr & 7) << 4);
    const bf16x8 af = *(const bf16x8*)((const char*)As + abyte);
#pragma unroll
    for (int nt = 0; nt < 2; ++nt) {
      const bf16x8 bfr = *(const bf16x8*)&Ws[wid * 32 + nt * 16 + lr][g * 8];
      acc[nt] = __builtin_amdgcn_mfma_f32_16x16x32_bf16(af, bfr, acc[nt], 0, 0, 0);
    }
    __syncthreads();
  }
}

// ---------------- q-proj fused with LN(tgt)+qpos; out bf16 scaled -------------
__global__ __launch_bounds__(256)
void qproj_kernel(const float* __restrict__ x, const float* __restrict__ lnw,
                  const float* __restrict__ lnb, const float* __restrict__ pos,
                  const u16* __restrict__ W, const float* __restrict__ bias,
                  u16* __restrict__ out, float scale)
{
  __shared__ u16 As[16 * 256];
  __shared__ u16 Ws[128][40];
  const int tid = threadIdx.x, lane = tid & 63, wid = tid >> 6;
  const int g = lane >> 4, lr = lane & 15;
  const int row0 = blockIdx.x * 16, n0 = blockIdx.y * 128;
  ln_stage<16>(x, row0, lnw, lnb, pos, As);
  f32x4 acc[2] = {};
  gemm16x128(As, W + (size_t)n0 * 256, Ws, acc);
#pragma unroll
  for (int nt = 0; nt < 2; ++nt) {
    const int col = n0 + wid * 32 + nt * 16 + lr;
    const float bv = bias[col];
#pragma unroll
    for (int r = 0; r < 4; ++r) {
      const int row = row0 + g * 4 + r;
      out[(size_t)row * 256 + col] = f2b((acc[nt][r] + bv) * scale);
    }
  }
}

// ---------------- sa_in fused: LN(tgt1)(+qpos for qk), N=768 ------------------
__global__ __launch_bounds__(256)
void sain_kernel(const float* __restrict__ x, const float* __restrict__ lnw,
                 const float* __restrict__ lnb, const float* __restrict__ pos,
                 const u16* __restrict__ W, const float* __restrict__ bias,
                 float* __restrict__ qkb, float* __restrict__ vsb)
{
  __shared__ u16 As[16 * 256];
  __shared__ u16 Ws[128][40];
  const int tid = threadIdx.x, lane = tid & 63, wid = tid >> 6;
  const int g = lane >> 4, lr = lane & 15;
  const int row0 = blockIdx.x * 16, y = blockIdx.y;
  ln_stage<16>(x, row0, lnw, lnb, (y < 4) ? pos : nullptr, As);
  f32x4 acc[2] = {};
  gemm16x128(As, W + (size_t)y * 128 * 256, Ws, acc);
#pragma unroll
  for (int nt = 0; nt < 2; ++nt) {
    const int cl = wid * 32 + nt * 16 + lr;
    const float bv = bias[y * 128 + cl];
#pragma unroll
    for (int r = 0; r < 4; ++r) {
      const int row = row0 + g * 4 + r;
      const float v = acc[nt][r] + bv;
      if (y < 4) qkb[(size_t)row * 512 + y * 128 + cl] = v;
      else       vsb[(size_t)row * 256 + (y - 4) * 128 + cl] = v;
    }
  }
}

// ---------------- FFN lin1 fused with LN(tgt2); GELU; out bf16 ---------------
__global__ __launch_bounds__(256)
void ffn1_kernel(const float* __restrict__ x, const float* __restrict__ lnw,
                 const float* __restrict__ lnb, const u16* __restrict__ W,
                 const float* __restrict__ bias, u16* __restrict__ out)
{
  __shared__ u16 As[64 * 256];
  __shared__ u16 Ws[256][40];
  const int tid = threadIdx.x, lane = tid & 63, wid = tid >> 6;
  const int g = lane >> 4, lr = lane & 15;
  const int row0 = blockIdx.x * 64, n0 = blockIdx.y * 256;
  ln_stage<64>(x, row0, lnw, lnb, nullptr, As);
  f32x4 acc[16] = {};
  for (int k0 = 0; k0 < 256; k0 += 32) {
    for (int cid = tid; cid < 1024; cid += 256) {
      const int r = cid >> 2, cg = (cid & 3) * 8;
      *(uint4*)&Ws[r][cg] = *(const uint4*)(W + (size_t)(n0 + r) * 256 + k0 + cg);
    }
    __syncthreads();
    const int arow = wid * 16 + lr;
    const int abyte = (arow * 512 + k0 * 2 + g * 16) ^ ((arow & 7) << 4);
    const bf16x8 af = *(const bf16x8*)((const char*)As + abyte);
#pragma unroll
    for (int nt = 0; nt < 16; ++nt) {
      const bf16x8 bfr = *(const bf16x8*)&Ws[nt * 16 + lr][g * 8];
      acc[nt] = __builtin_amdgcn_mfma_f32_16x16x32_bf16(af, bfr, acc[nt], 0, 0, 0);
    }
    __syncthreads();
  }
#pragma unroll
  for (int nt = 0; nt < 16; ++nt) {
    const int col = n0 + nt * 16 + lr;
    const float bv = bias[col];
#pragma unroll
    for (int r = 0; r < 4; ++r) {
      const int row = row0 + wid * 16 + g * 4 + r;
      float v = acc[nt][r] + bv;
      v = 0.5f * v * (1.f + erff(v * 0.70710678118654752f));
      out[(size_t)row * 2048 + col] = f2b(v);
    }
  }
}

// ---------------- Generic GEMM: C[M,N] = A[M,K] @ W[N,K]^T + bias -------------
template<int BM, int BN, int WM, int WN, int GELU_, int RES_, int OF32, int OBF>
__global__ __launch_bounds__(256)
void gemm_kernel(const u16* __restrict__ Ap, const u16* __restrict__ W,
                 const float* __restrict__ bias, const float* __restrict__ res,
                 float* __restrict__ Cf, u16* __restrict__ Cb,
                 int M, int N, int K, float scale)
{
  constexpr int WROWS = BM / WM;
  constexpr int WCOLS = BN / WN;
  constexpr int MT = WROWS / 16;
  constexpr int NT = WCOLS / 16;
  static_assert(WM * WN == 4, "4 waves");
  __shared__ u16 As[BM][40];
  __shared__ u16 Ws[BN][40];
  const int tid = threadIdx.x, lane = tid & 63, wid = tid >> 6;
  const int g = lane >> 4, lr = lane & 15;
  const int m0 = blockIdx.x * BM, n0 = blockIdx.y * BN;
  const int wm = wid / WN, wn = wid % WN;
  f32x4 acc[MT][NT] = {};
  for (int k0 = 0; k0 < K; k0 += 32) {
    for (int cid = tid; cid < BM * 4; cid += 256) {
      int r = cid >> 2, cg = (cid & 3) * 8;
      *(uint4*)&As[r][cg] = *(const uint4*)(Ap + (size_t)(m0 + r) * K + k0 + cg);
    }
    for (int cid = tid; cid < BN * 4; cid += 256) {
      int r = cid >> 2, cg = (cid & 3) * 8;
      *(uint4*)&Ws[r][cg] = *(const uint4*)(W + (size_t)(n0 + r) * K + k0 + cg);
    }
    __syncthreads();
    bf16x8 af[MT], bfr[NT];
#pragma unroll
    for (int mt = 0; mt < MT; ++mt) af[mt] = *(const bf16x8*)&As[wm * WROWS + mt * 16 + lr][g * 8];
#pragma unroll
    for (int nt = 0; nt < NT; ++nt) bfr[nt] = *(const bf16x8*)&Ws[wn * WCOLS + nt * 16 + lr][g * 8];
#pragma unroll
    for (int mt = 0; mt < MT; ++mt)
#pragma unroll
      for (int nt = 0; nt < NT; ++nt)
        acc[mt][nt] = __builtin_amdgcn_mfma_f32_16x16x32_bf16(af[mt], bfr[nt], acc[mt][nt], 0, 0, 0);
    __syncthreads();
  }
#pragma unroll
  for (int mt = 0; mt < MT; ++mt)
#pragma unroll
    for (int nt = 0; nt < NT; ++nt) {
      const int col = n0 + wn * WCOLS + nt * 16 + lr;
      const float bv = bias[col];
#pragma unroll
      for (int r = 0; r < 4; ++r) {
        const int row = m0 + wm * WROWS + mt * 16 + g * 4 + r;
        float v = (acc[mt][nt][r] + bv) * scale;
        if constexpr (GELU_) v = 0.5f * v * (1.f + erff(v * 0.70710678118654752f));
        if constexpr (RES_) v += res[(size_t)row * N + col];
        if constexpr (OF32) Cf[(size_t)row * N + col] = v;
        if constexpr (OBF) Cb[(size_t)row * N + col] = f2b(v);
      }
    }
}

// ---------------- KV projection GEMM — 3-barrier, paired-write epilogue -------
// V permutation within each 32-m block matches the swapped-QK PV k-slot order.
__global__ __launch_bounds__(512, 4)
void kv_gemm_kernel(const float* __restrict__ A, const u16* __restrict__ Wf,
                    const float* __restrict__ biasKV,
                    u16* __restrict__ Kb, u16* __restrict__ Vt)
{
  __shared__ u16 As[64 * 256];
  __shared__ u16 Vs[256 * 64];
  const int tid = threadIdx.x, lane = tid & 63, wid = tid >> 6;
  const int g = lane >> 4, lr = lane & 15;
  const int bidx = blockIdx.x / 85, t = blockIdx.x - bidx * 85;
  const int row0 = blockIdx.x * 64;

  for (int ch = tid; ch < 2048; ch += 512) {
    const int r = ch >> 5, c8 = (ch & 31) * 8;
    const float* ap = A + (size_t)(row0 + r) * 256 + c8;
    const float4 f0 = *(const float4*)ap;
    const float4 f1 = *(const float4*)(ap + 4);
    uint4 pk;
    pk.x = cvtpk(f0.x, f0.y);
    pk.y = cvtpk(f0.z, f0.w);
    pk.z = cvtpk(f1.x, f1.y);
    pk.w = cvtpk(f1.z, f1.w);
    const int byte = r * 512 + c8 * 2;
    *(uint4*)((char*)As + (byte ^ ((r & 7) << 4))) = pk;
  }
  __syncthreads();

  const u16* wbase = Wf + (size_t)wid * 8 * 4 * 512 + lane * 8;
  f32x4 acc[4][4] = {};
#pragma unroll 2
  for (int ks = 0; ks < 8; ++ks) {
    bf16x8 bfv[4], af[4];
#pragma unroll
    for (int nt = 0; nt < 4; ++nt)
      bfv[nt] = *(const bf16x8*)(wbase + (ks * 4 + nt) * 512);
#pragma unroll
    for (int mt = 0; mt < 4; ++mt) {
      const int r = mt * 16 + lr;
      const int byte = r * 512 + ks * 64 + g * 16;
      af[mt] = *(const bf16x8*)((const char*)As + (byte ^ ((r & 7) << 4)));
    }
#pragma unroll
    for (int mt = 0; mt < 4; ++mt)
#pragma unroll
      for (int nt = 0; nt < 4; ++nt)
        acc[mt][nt] = __builtin_amdgcn_mfma_f32_16x16x32_bf16(af[mt], bfv[nt], acc[mt][nt], 0, 0, 0);
  }

  const int isV = wid >> 2;
  if (isV) {
#pragma unroll
    for (int nt = 0; nt < 4; ++nt) {
      const int col = (wid - 4) * 64 + nt * 16 + lr;
      const float bv = biasKV[256 + col];
#pragma unroll
      for (int mt = 0; mt < 4; ++mt) {
        const int slot = (mt >> 1) * 32 + 16 * (mt & 1) + 8 * (g & 1) + 4 * (g >> 1);
#pragma unroll
        for (int r = 0; r < 4; r += 2) {
          const u32 val = cvtpk(acc[mt][nt][r] + bv, acc[mt][nt][r + 1] + bv);
          const int byte = (col * 128 + (slot + r) * 2) ^ ((col & 7) << 4);
          *(u32*)((char*)Vs + byte) = val;
        }
      }
    }
  }
  __syncthreads();

  if (!isV) {
#pragma unroll
    for (int nt = 0; nt < 4; ++nt) {
      const int col = wid * 64 + nt * 16 + lr;
      const float bv = biasKV[col];
#pragma unroll
      for (int mt = 0; mt < 4; ++mt)
#pragma unroll
        for (int r = 0; r < 4; r += 2) {
          const u32 pk = cvtpk(acc[mt][nt][r] + bv, acc[mt][nt][r + 1] + bv);
          const int rowA = mt * 16 + g * 4 + r;
          const int rowB = rowA + 1;
          *(u16*)((char*)As + ((rowA * 512 + col * 2) ^ ((rowA & 7) << 4))) = (u16)pk;
          *(u16*)((char*)As + ((rowB * 512 + col * 2) ^ ((rowB & 7) << 4))) = (u16)(pk >> 16);
        }
    }
  } else {
    const size_t vbase = (size_t)bidx * 256 * 5440 + (size_t)t * 64;
    const int t2 = tid - 256;
#pragma unroll
    for (int p = 0; p < 8; ++p) {
      const int idx = p * 256 + t2;
      const int col = idx >> 3, chunk = idx & 7;
      const int lbyte = col * 128 + ((chunk * 16) ^ ((col & 7) << 4));
      const uint4 v = *(const uint4*)((const char*)Vs + lbyte);
      *(uint4*)(Vt + vbase + (size_t)col * 5440 + chunk * 8) = v;
    }
  }
  __syncthreads();
#pragma unroll
  for (int p = 0; p < 4; ++p) {
    const int idx = p * 512 + tid;
    const int row = idx >> 5, c16 = idx & 31;
    const int lbyte = row * 512 + ((c16 * 16) ^ ((row & 7) << 4));
    const uint4 v = *(const uint4*)((const char*)As + lbyte);
    *(uint4*)(Kb + (size_t)(row0 + row) * 256 + c16 * 8) = v;
  }
}

// ---------------- Cross-attention: swapped-QK 32x32, register softmax ---------
// log2-domain softmax (scale & bias pre-multiplied by log2e); K/V prefetch;
// defer-max (THR=8). No LDS.
__global__ __launch_bounds__(256, 3)
void cross_attn_kernel(const u16* __restrict__ Q, const u16* __restrict__ Kb,
                       const u16* __restrict__ Vt, const uint4* __restrict__ biasT5,
                       u32* __restrict__ Opp, float* __restrict__ ML)
{
  const int tid = threadIdx.x, lane = tid & 63, wid = tid >> 6;
  const int ql = lane & 31, hh = lane >> 5;
  const int b = blockIdx.y, c = blockIdx.x;
  const int head = blockIdx.z * 4 + wid;
  const int m_base = c * (5440 / NCH);

  bf16x8 qf[4][2];
#pragma unroll
  for (int qb = 0; qb < 4; ++qb) {
    const int q = qb * 32 + ql;
#pragma unroll
    for (int hf = 0; hf < 2; ++hf)
      qf[qb][hf] = (q < 100)
        ? *(const bf16x8*)&Q[(size_t)(b * 100 + q) * 256 + head * 32 + hf * 16 + hh * 8]
        : zero8();
  }
  float M[4], L[4];
  f32x16 O[4];
#pragma unroll
  for (int qb = 0; qb < 4; ++qb) {
    M[qb] = -1e30f; L[qb] = 0.f;
#pragma unroll
    for (int i = 0; i < 16; ++i) O[qb][i] = 0.f;
  }

  const u16* kbase = &Kb[(size_t)(b * 5440 + m_base + ql) * 256 + head * 32 + hh * 8];
  const u16* vbase = &Vt[((size_t)(b * 8 + head) * 32 + ql) * 5440 + m_base + hh * 8];
  bf16x8 kf0 = *(const bf16x8*)kbase;
  bf16x8 kf1 = *(const bf16x8*)(kbase + 16);
  bf16x8 vf0 = *(const bf16x8*)vbase;
  bf16x8 vf1 = *(const bf16x8*)(vbase + 16);

  for (int s = 0; s < NSTEP; ++s) {
    // prefetch next step's K/V while computing this step
    bf16x8 nk0 = kf0, nk1 = kf1, nv0 = vf0, nv1 = vf1;
    if (s + 1 < NSTEP) {
      const u16* kp = kbase + (size_t)(s + 1) * 32 * 256;
      const u16* vp = vbase + (s + 1) * 32;
      nk0 = *(const bf16x8*)kp;
      nk1 = *(const bf16x8*)(kp + 16);
      nv0 = *(const bf16x8*)vp;
      nv1 = *(const bf16x8*)(vp + 16);
    }
    const uint4* bb = biasT5 + ((size_t)(b * 170 + c * NSTEP + s) * 4) * 128 + lane;
#pragma unroll
    for (int qb = 0; qb < 4; ++qb) {
      const uint4 b0 = bb[qb * 128];
      const uint4 b1 = bb[qb * 128 + 64];
      f32x16 Sv = {};
      __builtin_amdgcn_s_setprio(1);
      Sv = __builtin_amdgcn_mfma_f32_32x32x16_bf16(kf0, qf[qb][0], Sv, 0, 0, 0);
      Sv = __builtin_amdgcn_mfma_f32_32x32x16_bf16(kf1, qf[qb][1], Sv, 0, 0, 0);
      __builtin_amdgcn_s_setprio(0);
      const u32 bw[8] = {b0.x, b0.y, b0.z, b0.w, b1.x, b1.y, b1.z, b1.w};
#pragma unroll
      for (int i = 0; i < 8; ++i) {
        Sv[2 * i]     += b2f((u16)bw[i]);
        Sv[2 * i + 1] += b2f((u16)(bw[i] >> 16));
      }
      // max over 16 in-lane (tree) + partner half
      float t8[8];
#pragma unroll
      for (int i = 0; i < 8; ++i) t8[i] = fmaxf(Sv[2 * i], Sv[2 * i + 1]);
      float t4a = fmaxf(fmaxf(t8[0], t8[1]), fmaxf(t8[2], t8[3]));
      float t4b = fmaxf(fmaxf(t8[4], t8[5]), fmaxf(t8[6], t8[7]));
      float mx = fmaxf(t4a, t4b);
      mx = fmaxf(mx, __shfl_xor(mx, 32));
      // defer-max: only rescale when max grew by more than THR (log2 units)
      if (!__all(mx - M[qb] <= 8.f)) {
        const float newM = fmaxf(M[qb], mx);
        const float al = exp2f(M[qb] - newM);
        M[qb] = newM;
        L[qb] *= al;
#pragma unroll
        for (int i = 0; i < 16; ++i) O[qb][i] *= al;
      }
      float p[16];
#pragma unroll
      for (int i = 0; i < 16; ++i) p[i] = exp2f(Sv[i] - M[qb]);
      float s8[8];
#pragma unroll
      for (int i = 0; i < 8; ++i) s8[i] = p[2 * i] + p[2 * i + 1];
      L[qb] += ((s8[0] + s8[1]) + (s8[2] + s8[3])) + ((s8[4] + s8[5]) + (s8[6] + s8[7]));
      union { uint4 u; bf16x8 v; } pb0, pb1;
      pb0.u.x = cvtpk(p[0], p[1]);   pb0.u.y = cvtpk(p[2], p[3]);
      pb0.u.z = cvtpk(p[4], p[5]);   pb0.u.w = cvtpk(p[6], p[7]);
      pb1.u.x = cvtpk(p[8], p[9]);   pb1.u.y = cvtpk(p[10], p[11]);
      pb1.u.z = cvtpk(p[12], p[13]); pb1.u.w = cvtpk(p[14], p[15]);
      __builtin_amdgcn_s_setprio(1);
      O[qb] = __builtin_amdgcn_mfma_f32_32x32x16_bf16(vf0, pb0.v, O[qb], 0, 0, 0);
      O[qb] = __builtin_amdgcn_mfma_f32_32x32x16_bf16(vf1, pb1.v, O[qb], 0, 0, 0);
      __builtin_amdgcn_s_setprio(0);
    }
    kf0 = nk0; kf1 = nk1; vf0 = nv0; vf1 = nv1;
  }
  const int bh = b * 8 + head;
#pragma unroll
  for (int qb = 0; qb < 4; ++qb) {
    const int q = qb * 32 + ql;
    const float Lt = L[qb] + __shfl_xor(L[qb], 32);
    if (q < 100) {
      const size_t rb = (size_t)(bh * NCH + c) * 128 + q;
#pragma unroll
      for (int i = 0; i < 8; ++i)
        Opp[rb * 16 + hh * 8 + i] = cvtpk(O[qb][2 * i], O[qb][2 * i + 1]);
      if (hh == 0) { ML[rb * 2] = M[qb]; ML[rb * 2 + 1] = Lt; }
    }
  }
}

// ---------------- Combine cross-attn partials -> attn_out bf16 [1600,256] ------
// decode: output d -> reg = (d&3)+4*(d>>3), hh = (d>>2)&1, slot = hh*8+(reg>>1)
// M values are in log2 domain -> exp2f.
__global__ __launch_bounds__(256)
void reduce_attn_kernel(const u32* __restrict__ Opp, const float* __restrict__ ML,
                        u16* __restrict__ outb)
{
  const int row = blockIdx.x;            // 0..1599
  const int b = row / 100, q = row % 100;
  const int h = threadIdx.x >> 5, d = threadIdx.x & 31;
  const int bh = b * 8 + h;
  const int reg = (d & 3) + 4 * (d >> 3);
  const int slot = ((d >> 2) & 1) * 8 + (reg >> 1);
  const int half = reg & 1;
  float gm = -1e30f;
  for (int c = 0; c < NCH; ++c) gm = fmaxf(gm, ML[((size_t)(bh * NCH + c) * 128 + q) * 2]);
  float l = 0.f, o = 0.f;
  for (int c = 0; c < NCH; ++c) {
    const size_t rb = (size_t)(bh * NCH + c) * 128 + q;
    const float w = exp2f(ML[rb * 2] - gm);
    l += ML[rb * 2 + 1] * w;
    const u32 pv = Opp[rb * 16 + slot];
    o += b2f((u16)(half ? (pv >> 16) : pv)) * w;
  }
  outb[(size_t)row * 256 + h * 32 + d] = f2b(o / l);
}

// ---------------- Self-attention (NQ=100, tiny) ----------------
__global__ __launch_bounds__(128)
void self_attn_kernel(const float* __restrict__ qk, const float* __restrict__ vs,
                      u16* __restrict__ so)
{
  __shared__ u16 kk[100][36];
  __shared__ u16 vv[100][36];
  __shared__ float S[100][101];
  const int b = blockIdx.x >> 3, h = blockIdx.x & 7;
  const int t = threadIdx.x;
  for (int e = t; e < 3200; e += 128) {
    const int r = e >> 5, cq = e & 31;
    kk[r][cq] = f2b(qk[(size_t)(b * 100 + r) * 512 + 256 + h * 32 + cq]);
    vv[r][cq] = f2b(vs[(size_t)(b * 100 + r) * 256 + h * 32 + cq]);
  }
  __syncthreads();
  if (t < 100) {
    float qr_[32];
#pragma unroll
    for (int cq = 0; cq < 32; ++cq) qr_[cq] = qk[(size_t)(b * 100 + t) * 512 + h * 32 + cq];
    for (int m = 0; m < 100; ++m) {
      float dp = 0.f;
#pragma unroll
      for (int cq = 0; cq < 32; ++cq) dp += qr_[cq] * b2f(kk[m][cq]);
      S[t][m] = dp * 0.17677669529663687f;
    }
    float mx = -1e30f;
    for (int m = 0; m < 100; ++m) mx = fmaxf(mx, S[t][m]);
    float sum = 0.f;
    for (int m = 0; m < 100; ++m) { const float p = __expf(S[t][m] - mx); S[t][m] = p; sum += p; }
    const float inv = 1.f / sum;
    float o[32];
#pragma unroll
    for (int cq = 0; cq < 32; ++cq) o[cq] = 0.f;
    for (int m = 0; m < 100; ++m) {
      const float p = S[t][m];
#pragma unroll
      for (int cq = 0; cq < 32; ++cq) o[cq] += p * b2f(vv[m][cq]);
    }
#pragma unroll
    for (int cq = 0; cq < 32; ++cq)
      so[(size_t)(b * 100 + t) * 256 + h * 32 + cq] = f2b(o[cq] * inv);
  }
}

// ---------------- mask_logits: per-b [100,256] @ hr[b][4096,256]^T -------------
__global__ __launch_bounds__(256)
void mask_gemm_kernel(const u16* __restrict__ tm, const float* __restrict__ hr,
                      float* __restrict__ out)
{
  __shared__ u16 As[112][40];
  __shared__ u16 Bs[64][40];
  const int tid = threadIdx.x, lane = tid & 63, wid = tid >> 6;
  const int g = lane >> 4, lr = lane & 15;
  const int b = blockIdx.y, n0 = blockIdx.x * 64;
  f32x4 acc[7] = {};
  for (int k0 = 0; k0 < 256; k0 += 32) {
    for (int cid = tid; cid < 448; cid += 256) {
      const int r = cid >> 2, cg = (cid & 3) * 8;
      uint4 val = {0u, 0u, 0u, 0u};
      if (r < 100) val = *(const uint4*)&tm[(size_t)(b * 100 + r) * 256 + k0 + cg];
      *(uint4*)&As[r][cg] = val;
    }
    {
      const int r = tid >> 2, cg = (tid & 3) * 8;
      const float* hp = hr + (size_t)(b * 4096 + n0 + r) * 256 + k0 + cg;
      float4 f0 = *(const float4*)hp;
      float4 f1 = *(const float4*)(hp + 4);
      uint4 pk;
      pk.x = cvtpk(f0.x, f0.y); pk.y = cvtpk(f0.z, f0.w);
      pk.z = cvtpk(f1.x, f1.y); pk.w = cvtpk(f1.z, f1.w);
      *(uint4*)&Bs[r][cg] = pk;
    }
    __syncthreads();
    const bf16x8 bfr = *(const bf16x8*)&Bs[wid * 16 + lr][g * 8];
#pragma unroll
    for (int mt = 0; mt < 7; ++mt) {
      const bf16x8 af = *(const bf16x8*)&As[mt * 16 + lr][g * 8];
      acc[mt] = __builtin_amdgcn_mfma_f32_16x16x32_bf16(af, bfr, acc[mt], 0, 0, 0);
    }
    __syncthreads();
  }
#pragma unroll
  for (int mt = 0; mt < 7; ++mt)
#pragma unroll
    for (int r = 0; r < 4; ++r) {
      const int qr = mt * 16 + g * 4 + r;
      if (qr < 100)
        out[(size_t)(b * 100 + qr) * 4096 + n0 + wid * 16 + lr] = acc[mt][r];
    }
}

// =======================================================================
extern "C" void kernel_launch(void* const* d_in, const int* in_sizes, int n_in,
                              void* d_out, int out_size, void* d_ws, size_t ws_size,
                              hipStream_t stream)
{
  (void)in_sizes; (void)n_in; (void)out_size; (void)ws_size;
  const float* tgt      = (const float*)d_in[0];
  const float* memory   = (const float*)d_in[1];
  const float* memhr    = (const float*)d_in[2];
  const float* pbias    = (const float*)d_in[3];
  const float* qpos     = (const float*)d_in[4];
  const float* lncw     = (const float*)d_in[5];
  const float* lncb     = (const float*)d_in[6];
  const float* q_w      = (const float*)d_in[7];
  const float* q_b      = (const float*)d_in[8];
  const float* k_w      = (const float*)d_in[9];
  const float* k_b      = (const float*)d_in[10];
  const float* v_w      = (const float*)d_in[11];
  const float* v_b      = (const float*)d_in[12];
  const float* out_w    = (const float*)d_in[13];
  const float* out_b    = (const float*)d_in[14];
  const float* lnsw     = (const float*)d_in[15];
  const float* lnsb     = (const float*)d_in[16];
  const float* sa_in_w  = (const float*)d_in[17];
  const float* sa_in_b  = (const float*)d_in[18];
  const float* sa_out_w = (const float*)d_in[19];
  const float* sa_out_b = (const float*)d_in[20];
  const float* lnfw     = (const float*)d_in[21];
  const float* lnfb     = (const float*)d_in[22];
  const float* l1w      = (const float*)d_in[23];
  const float* l1b      = (const float*)d_in[24];
  const float* l2w      = (const float*)d_in[25];
  const float* l2b      = (const float*)d_in[26];
  const float* me_w     = (const float*)d_in[27];
  const float* me_b     = (const float*)d_in[28];
  float* outf = (float*)d_out;

  char* ws = (char*)d_ws;
  size_t off = 0;
  auto alloc = [&](size_t bytes) -> void* {
    void* p = ws + off;
    off = (off + bytes + 255) & ~(size_t)255;
    return p;
  };
  u16*   Wf    = (u16*)alloc((size_t)131072 * 2);
  u16*   qW    = (u16*)alloc((size_t)65536 * 2);
  u16*   outW  = (u16*)alloc((size_t)65536 * 2);
  u16*   saW   = (u16*)alloc((size_t)196608 * 2);
  u16*   saoW  = (u16*)alloc((size_t)65536 * 2);
  u16*   l1W   = (u16*)alloc((size_t)524288 * 2);
  u16*   l2W   = (u16*)alloc((size_t)524288 * 2);
  u16*   meW   = (u16*)alloc((size_t)65536 * 2);
  float* kvB   = (float*)alloc((size_t)512 * 4);
  uint4* biasT5= (uint4*)alloc((size_t)16 * 170 * 4 * 128 * 16);
  u16*   Qb    = (u16*)alloc((size_t)409600 * 2);
  u16*   Kb    = (u16*)alloc((size_t)22282240 * 2);
  u16*   Vt    = (u16*)alloc((size_t)22282240 * 2);
  u32*   Opp   = (u32*)alloc((size_t)(128 * NCH * 128 * 16) * 4);
  float* MLp   = (float*)alloc((size_t)(128 * NCH * 128 * 2) * 4);
  u16*   attno = (u16*)alloc((size_t)409600 * 2);
  float* tgt1  = (float*)alloc((size_t)409600 * 4);
  float* qkb   = (float*)alloc((size_t)819200 * 4);
  float* vsb   = (float*)alloc((size_t)409600 * 4);
  u16*   sob   = (u16*)alloc((size_t)409600 * 2);
  float* tgt2  = (float*)alloc((size_t)409600 * 4);
  u16*   hb    = (u16*)alloc((size_t)3276800 * 2);
  u16*   t3b   = (u16*)alloc((size_t)409600 * 2);
  u16*   tmb   = (u16*)alloc((size_t)409600 * 2);

  const float SCALE = 0.17677669529663687f * LOG2E;  // 32^-0.5 * log2(e)

  // ---- single prep launch ----
  PrepArgs pa;
  pa.seg[0] = {q_w,      qW,   16384};
  pa.seg[1] = {out_w,    outW, 16384};
  pa.seg[2] = {sa_in_w,  saW,  49152};
  pa.seg[3] = {sa_out_w, saoW, 16384};
  pa.seg[4] = {l1w,      l1W,  131072};
  pa.seg[5] = {l2w,      l2W,  131072};
  pa.seg[6] = {me_w,     meW,  16384};
  pa.k_w = k_w; pa.v_w = v_w; pa.k_b = k_b; pa.v_b = v_b; pa.pbias = pbias;
  pa.Wf = Wf; pa.biasT5 = biasT5; pa.kvB = kvB;
  prep_kernel<<<4258, 256, 0, stream>>>(pa);

  // ---- cross attention ----
  qproj_kernel<<<dim3(100, 2), 256, 0, stream>>>(tgt, lncw, lncb, qpos, qW, q_b, Qb, SCALE);
  kv_gemm_kernel<<<dim3(1360), 512, 0, stream>>>(memory, Wf, kvB, Kb, Vt);
  cross_attn_kernel<<<dim3(NCH, 16, 2), 256, 0, stream>>>(Qb, Kb, Vt, biasT5, Opp, MLp);
  reduce_attn_kernel<<<1600, 256, 0, stream>>>(Opp, MLp, attno);
  gemm_kernel<16, 128, 1, 4, 0, 1, 1, 0><<<dim3(100, 2), 256, 0, stream>>>(
      attno, outW, out_b, tgt, tgt1, nullptr, 1600, 256, 256, 1.f);

  // ---- self attention ----
  sain_kernel<<<dim3(100, 6), 256, 0, stream>>>(tgt1, lnsw, lnsb, qpos, saW, sa_in_b, qkb, vsb);
  self_attn_kernel<<<128, 128, 0, stream>>>(qkb, vsb, sob);
  gemm_kernel<16, 128, 1, 4, 0, 1, 1, 0><<<dim3(100, 2), 256, 0, stream>>>(
      sob, saoW, sa_out_b, tgt1, tgt2, nullptr, 1600, 256, 256, 1.f);

  // ---- FFN ----
  ffn1_kernel<<<dim3(25, 8), 256, 0, stream>>>(tgt2, lnfw, lnfb, l1W, l1b, hb);
  gemm_kernel<16, 128, 1, 4, 0, 1, 1, 1><<<dim3(100, 2), 256, 0, stream>>>(
      hb, l2W, l2b, tgt2, outf, t3b, 1600, 256, 2048, 1.f);

  // ---- mask branch ----
  gemm_kernel<16, 128, 1, 4, 0, 0, 0, 1><<<dim3(100, 2), 256, 0, stream>>>(
      t3b, meW, me_b, nullptr, nullptr, tmb, 1600, 256, 256, 1.f);
  mask_gemm_kernel<<<dim3(64, 16), 256, 0, stream>>>(tmb, memhr, outf + 409600);
}

// Round 12
// 341.605 us; speedup vs baseline: 1.1399x; 1.1399x over previous
//
#include <hip/hip_runtime.h>

typedef unsigned short u16;
typedef unsigned int u32;
typedef __bf16 bf16x8 __attribute__((ext_vector_type(8)));
typedef float f32x4 __attribute__((ext_vector_type(4)));
typedef float f32x16 __attribute__((ext_vector_type(16)));

#define NCH 34   // cross-attn split-K chunks (m-chunk = 160, 5 steps of 32)
#define NSTEP 5

__device__ __forceinline__ u16 f2b(float f) {
  u32 u = __float_as_uint(f);
  u32 r = (u + 0x7fffu + ((u >> 16) & 1u)) >> 16;   // RNE, inputs finite
  return (u16)r;
}
__device__ __forceinline__ float b2f(u16 h) {
  return __uint_as_float(((u32)h) << 16);
}
__device__ __forceinline__ bf16x8 zero8() {
  union { uint4 u; bf16x8 v; } z; z.u = make_uint4(0u, 0u, 0u, 0u); return z.v;
}
__device__ __forceinline__ u32 cvtpk(float lo, float hi) {
  u32 r;
  asm("v_cvt_pk_bf16_f32 %0, %1, %2" : "=v"(r) : "v"(lo), "v"(hi));
  return r;
}

// ================= PREP: weight cvt + Wf pack + bias pack + bias repack =======
struct Seg { const float* in; u16* out; int n4; };
struct PrepArgs {
  Seg seg[7];
  const float *k_w, *v_w, *k_b, *v_b, *pbias;
  u16 *Wf;
  uint4 *biasT5;
  float *kvB;
};

// grid: [0,1472) f2b | [1472,1536) Wf pack | [1536,1538) kv bias | [1538,4258) bias repack
__global__ __launch_bounds__(256)
void prep_kernel(PrepArgs a)
{
  __shared__ float S[100][34];
  const int bx = blockIdx.x, tid = threadIdx.x;
  if (bx < 1472) {
    int bxr = bx;
#pragma unroll
    for (int k = 0; k < 7; ++k) {
      const int nb = a.seg[k].n4 >> 8;
      if (bxr < nb) {
        const int i = bxr * 256 + tid;
        const float4 f = *(const float4*)(a.seg[k].in + (size_t)i * 4);
        uint2 pk; pk.x = cvtpk(f.x, f.y); pk.y = cvtpk(f.z, f.w);
        *(uint2*)(a.seg[k].out + (size_t)i * 4) = pk;
        return;
      }
      bxr -= nb;
    }
    return;
  } else if (bx < 1536) {
    // fragment-major pack: Wf[((gI*8+ks)*4+nt)*512 + lane*8 + j]
    const int i = bx - 1472, gI = i >> 3, ks = i & 7;
    const int nt = tid >> 6, lane = tid & 63, lr = lane & 15, g = lane >> 4;
    const float* src = (gI < 4 ? a.k_w + (size_t)(gI * 64 + nt * 16 + lr) * 256
                               : a.v_w + (size_t)((gI - 4) * 64 + nt * 16 + lr) * 256)
                       + ks * 32 + g * 8;
    const float4 f0 = *(const float4*)src;
    const float4 f1 = *(const float4*)(src + 4);
    uint4 pk;
    pk.x = cvtpk(f0.x, f0.y); pk.y = cvtpk(f0.z, f0.w);
    pk.z = cvtpk(f1.x, f1.y); pk.w = cvtpk(f1.z, f1.w);
    *(uint4*)(a.Wf + (size_t)((gI * 8 + ks) * 4 + nt) * 512 + lane * 8) = pk;
  } else if (bx < 1538) {
    const int i = (bx - 1536) * 256 + tid;
    a.kvB[i] = (i < 256) ? a.k_b[i] : a.v_b[i - 256];
  } else {
    // bias repack for swapped-QK: biasT5[bt][qb][half][lane] uint4 (bt = b*170+sg)
    // lane (q = qb*32 + lane&31, hh = lane>>5) holds 16 bf16 in S-reg order:
    //   reg = half*8+i -> m = (reg&3) + 8*(reg>>2) + 4*hh
    const int bt = bx - 1538;          // 0..2719
    const int b = bt / 170, sg = bt - b * 170;
    const int m0 = sg * 32;
    for (int idx = tid; idx < 800; idx += 256) {
      const int q = idx >> 3, seg = idx & 7;
      const float4 v = *(const float4*)(a.pbias + (size_t)(b * 100 + q) * 5440 + m0 + seg * 4);
      S[q][seg * 4 + 0] = v.x; S[q][seg * 4 + 1] = v.y;
      S[q][seg * 4 + 2] = v.z; S[q][seg * 4 + 3] = v.w;
    }
    __syncthreads();
#pragma unroll
    for (int pass = 0; pass < 2; ++pass) {
      const int idx = pass * 256 + tid;
      const int qb = idx >> 7, r2 = idx & 127;
      const int half = r2 >> 6, lane = r2 & 63;
      const int q = qb * 32 + (lane & 31), hh = lane >> 5;
      u16 hv[8];
#pragma unroll
      for (int i = 0; i < 8; ++i) {
        const int reg = half * 8 + i;
        const int m = (reg & 3) + 8 * (reg >> 2) + 4 * hh;
        hv[i] = (q < 100) ? f2b(S[q][m]) : (u16)0;
      }
      uint4 pk;
      pk.x = (u32)hv[0] | ((u32)hv[1] << 16);
      pk.y = (u32)hv[2] | ((u32)hv[3] << 16);
      pk.z = (u32)hv[4] | ((u32)hv[5] << 16);
      pk.w = (u32)hv[6] | ((u32)hv[7] << 16);
      a.biasT5[((size_t)(bt * 4 + qb)) * 128 + half * 64 + lane] = pk;
    }
  }
}

// ---------------- LN staging into swizzled bf16 LDS tile [ROWS][256] ----------
template<int ROWS>
__device__ __forceinline__ void ln_stage(const float* __restrict__ x, int row0,
    const float* __restrict__ w, const float* __restrict__ b,
    const float* __restrict__ pos, u16* As)
{
  const int tid = threadIdx.x, lane = tid & 63, wid = tid >> 6;
  const float4 wv = *(const float4*)(w + lane * 4);
  const float4 bv = *(const float4*)(b + lane * 4);
#pragma unroll
  for (int rr = 0; rr < ROWS / 4; ++rr) {
    const int rl = wid * (ROWS / 4) + rr;
    const size_t o = (size_t)(row0 + rl) * 256 + lane * 4;
    const float4 v = *(const float4*)(x + o);
    float s = v.x + v.y + v.z + v.w;
#pragma unroll
    for (int m = 1; m < 64; m <<= 1) s += __shfl_xor(s, m);
    const float mean = s * (1.f / 256.f);
    const float d0 = v.x - mean, d1 = v.y - mean, d2 = v.z - mean, d3 = v.w - mean;
    float ss = d0 * d0 + d1 * d1 + d2 * d2 + d3 * d3;
#pragma unroll
    for (int m = 1; m < 64; m <<= 1) ss += __shfl_xor(ss, m);
    const float rs = rsqrtf(ss * (1.f / 256.f) + 1e-5f);
    float y0 = d0 * rs * wv.x + bv.x;
    float y1 = d1 * rs * wv.y + bv.y;
    float y2 = d2 * rs * wv.z + bv.z;
    float y3 = d3 * rs * wv.w + bv.w;
    if (pos) {
      const float4 pv = *(const float4*)(pos + o);
      y0 += pv.x; y1 += pv.y; y2 += pv.z; y3 += pv.w;
    }
    uint2 pk; pk.x = cvtpk(y0, y1); pk.y = cvtpk(y2, y3);
    const int byte = (rl * 512 + lane * 8) ^ ((rl & 7) << 4);
    *(uint2*)((char*)As + byte) = pk;
  }
}

// 16x128 GEMM loop reading A from full-K swizzled LDS; W staged per k0.
__device__ __forceinline__ void gemm16x128(const u16* As, const u16* __restrict__ W,
                                           u16 (*Ws)[40], f32x4 acc[2])
{
  const int tid = threadIdx.x, lane = tid & 63, wid = tid >> 6;
  const int g = lane >> 4, lr = lane & 15;
  for (int k0 = 0; k0 < 256; k0 += 32) {
    for (int cid = tid; cid < 512; cid += 256) {
      const int r = cid >> 2, cg = (cid & 3) * 8;
      *(uint4*)&Ws[r][cg] = *(const uint4*)(W + (size_t)r * 256 + k0 + cg);
    }
    __syncthreads();
    const int abyte = (lr * 512 + k0 * 2 + g * 16) ^ ((lr & 7) << 4);
    const bf16x8 af = *(const bf16x8*)((const char*)As + abyte);
#pragma unroll
    for (int nt = 0; nt < 2; ++nt) {
      const bf16x8 bfr = *(const bf16x8*)&Ws[wid * 32 + nt * 16 + lr][g * 8];
      acc[nt] = __builtin_amdgcn_mfma_f32_16x16x32_bf16(af, bfr, acc[nt], 0, 0, 0);
    }
    __syncthreads();
  }
}

// ---------------- q-proj fused with LN(tgt)+qpos; out bf16 scaled -------------
__global__ __launch_bounds__(256)
void qproj_kernel(const float* __restrict__ x, const float* __restrict__ lnw,
                  const float* __restrict__ lnb, const float* __restrict__ pos,
                  const u16* __restrict__ W, const float* __restrict__ bias,
                  u16* __restrict__ out, float scale)
{
  __shared__ u16 As[16 * 256];
  __shared__ u16 Ws[128][40];
  const int tid = threadIdx.x, lane = tid & 63, wid = tid >> 6;
  const int g = lane >> 4, lr = lane & 15;
  const int row0 = blockIdx.x * 16, n0 = blockIdx.y * 128;
  ln_stage<16>(x, row0, lnw, lnb, pos, As);
  f32x4 acc[2] = {};
  gemm16x128(As, W + (size_t)n0 * 256, Ws, acc);
#pragma unroll
  for (int nt = 0; nt < 2; ++nt) {
    const int col = n0 + wid * 32 + nt * 16 + lr;
    const float bv = bias[col];
#pragma unroll
    for (int r = 0; r < 4; ++r) {
      const int row = row0 + g * 4 + r;
      out[(size_t)row * 256 + col] = f2b((acc[nt][r] + bv) * scale);
    }
  }
}

// ---------------- sa_in fused: LN(tgt1)(+qpos for qk), N=768 ------------------
__global__ __launch_bounds__(256)
void sain_kernel(const float* __restrict__ x, const float* __restrict__ lnw,
                 const float* __restrict__ lnb, const float* __restrict__ pos,
                 const u16* __restrict__ W, const float* __restrict__ bias,
                 float* __restrict__ qkb, float* __restrict__ vsb)
{
  __shared__ u16 As[16 * 256];
  __shared__ u16 Ws[128][40];
  const int tid = threadIdx.x, lane = tid & 63, wid = tid >> 6;
  const int g = lane >> 4, lr = lane & 15;
  const int row0 = blockIdx.x * 16, y = blockIdx.y;
  ln_stage<16>(x, row0, lnw, lnb, (y < 4) ? pos : nullptr, As);
  f32x4 acc[2] = {};
  gemm16x128(As, W + (size_t)y * 128 * 256, Ws, acc);
#pragma unroll
  for (int nt = 0; nt < 2; ++nt) {
    const int cl = wid * 32 + nt * 16 + lr;
    const float bv = bias[y * 128 + cl];
#pragma unroll
    for (int r = 0; r < 4; ++r) {
      const int row = row0 + g * 4 + r;
      const float v = acc[nt][r] + bv;
      if (y < 4) qkb[(size_t)row * 512 + y * 128 + cl] = v;
      else       vsb[(size_t)row * 256 + (y - 4) * 128 + cl] = v;
    }
  }
}

// ---------------- FFN lin1 fused with LN(tgt2); GELU; out bf16 ---------------
__global__ __launch_bounds__(256)
void ffn1_kernel(const float* __restrict__ x, const float* __restrict__ lnw,
                 const float* __restrict__ lnb, const u16* __restrict__ W,
                 const float* __restrict__ bias, u16* __restrict__ out)
{
  __shared__ u16 As[64 * 256];
  __shared__ u16 Ws[256][40];
  const int tid = threadIdx.x, lane = tid & 63, wid = tid >> 6;
  const int g = lane >> 4, lr = lane & 15;
  const int row0 = blockIdx.x * 64, n0 = blockIdx.y * 256;
  ln_stage<64>(x, row0, lnw, lnb, nullptr, As);
  f32x4 acc[16] = {};
  for (int k0 = 0; k0 < 256; k0 += 32) {
    for (int cid = tid; cid < 1024; cid += 256) {
      const int r = cid >> 2, cg = (cid & 3) * 8;
      *(uint4*)&Ws[r][cg] = *(const uint4*)(W + (size_t)(n0 + r) * 256 + k0 + cg);
    }
    __syncthreads();
    const int arow = wid * 16 + lr;
    const int abyte = (arow * 512 + k0 * 2 + g * 16) ^ ((arow & 7) << 4);
    const bf16x8 af = *(const bf16x8*)((const char*)As + abyte);
#pragma unroll
    for (int nt = 0; nt < 16; ++nt) {
      const bf16x8 bfr = *(const bf16x8*)&Ws[nt * 16 + lr][g * 8];
      acc[nt] = __builtin_amdgcn_mfma_f32_16x16x32_bf16(af, bfr, acc[nt], 0, 0, 0);
    }
    __syncthreads();
  }
#pragma unroll
  for (int nt = 0; nt < 16; ++nt) {
    const int col = n0 + nt * 16 + lr;
    const float bv = bias[col];
#pragma unroll
    for (int r = 0; r < 4; ++r) {
      const int row = row0 + wid * 16 + g * 4 + r;
      float v = acc[nt][r] + bv;
      v = 0.5f * v * (1.f + erff(v * 0.70710678118654752f));
      out[(size_t)row * 2048 + col] = f2b(v);
    }
  }
}

// ---------------- Generic GEMM: C[M,N] = A[M,K] @ W[N,K]^T + bias -------------
template<int BM, int BN, int WM, int WN, int GELU_, int RES_, int OF32, int OBF>
__global__ __launch_bounds__(256)
void gemm_kernel(const u16* __restrict__ Ap, const u16* __restrict__ W,
                 const float* __restrict__ bias, const float* __restrict__ res,
                 float* __restrict__ Cf, u16* __restrict__ Cb,
                 int M, int N, int K, float scale)
{
  constexpr int WROWS = BM / WM;
  constexpr int WCOLS = BN / WN;
  constexpr int MT = WROWS / 16;
  constexpr int NT = WCOLS / 16;
  static_assert(WM * WN == 4, "4 waves");
  __shared__ u16 As[BM][40];
  __shared__ u16 Ws[BN][40];
  const int tid = threadIdx.x, lane = tid & 63, wid = tid >> 6;
  const int g = lane >> 4, lr = lane & 15;
  const int m0 = blockIdx.x * BM, n0 = blockIdx.y * BN;
  const int wm = wid / WN, wn = wid % WN;
  f32x4 acc[MT][NT] = {};
  for (int k0 = 0; k0 < K; k0 += 32) {
    for (int cid = tid; cid < BM * 4; cid += 256) {
      int r = cid >> 2, cg = (cid & 3) * 8;
      *(uint4*)&As[r][cg] = *(const uint4*)(Ap + (size_t)(m0 + r) * K + k0 + cg);
    }
    for (int cid = tid; cid < BN * 4; cid += 256) {
      int r = cid >> 2, cg = (cid & 3) * 8;
      *(uint4*)&Ws[r][cg] = *(const uint4*)(W + (size_t)(n0 + r) * K + k0 + cg);
    }
    __syncthreads();
    bf16x8 af[MT], bfr[NT];
#pragma unroll
    for (int mt = 0; mt < MT; ++mt) af[mt] = *(const bf16x8*)&As[wm * WROWS + mt * 16 + lr][g * 8];
#pragma unroll
    for (int nt = 0; nt < NT; ++nt) bfr[nt] = *(const bf16x8*)&Ws[wn * WCOLS + nt * 16 + lr][g * 8];
#pragma unroll
    for (int mt = 0; mt < MT; ++mt)
#pragma unroll
      for (int nt = 0; nt < NT; ++nt)
        acc[mt][nt] = __builtin_amdgcn_mfma_f32_16x16x32_bf16(af[mt], bfr[nt], acc[mt][nt], 0, 0, 0);
    __syncthreads();
  }
#pragma unroll
  for (int mt = 0; mt < MT; ++mt)
#pragma unroll
    for (int nt = 0; nt < NT; ++nt) {
      const int col = n0 + wn * WCOLS + nt * 16 + lr;
      const float bv = bias[col];
#pragma unroll
      for (int r = 0; r < 4; ++r) {
        const int row = m0 + wm * WROWS + mt * 16 + g * 4 + r;
        float v = (acc[mt][nt][r] + bv) * scale;
        if constexpr (GELU_) v = 0.5f * v * (1.f + erff(v * 0.70710678118654752f));
        if constexpr (RES_) v += res[(size_t)row * N + col];
        if constexpr (OF32) Cf[(size_t)row * N + col] = v;
        if constexpr (OBF) Cb[(size_t)row * N + col] = f2b(v);
      }
    }
}

// ---------------- KV projection GEMM — BM=32, 4 blocks/CU ----------------
// 2720 blocks x 512 thr; block = 32 rows x 512 cols (K 0-255 | V 256-511).
// A bf16 in As full-K (16 KB swizzled); W via fragment-major Wf (L2-resident).
// V assembled into padded Vs[256][36] (stride-18 banks, conflict-free) with the
// swapped-QK 32-block permutation p(m) = (m&3)+4*((m>>3)&1)+8*((m>>2)&1)+16*(m>>4);
// K assembled into As; both coop-stored coalesced. 3 barriers total.
__global__ __launch_bounds__(512, 4)
void kv_gemm_kernel(const float* __restrict__ A, const u16* __restrict__ Wf,
                    const float* __restrict__ biasKV,
                    u16* __restrict__ Kb, u16* __restrict__ Vt)
{
  __shared__ u16 As[32 * 256];      // 16 KB
  __shared__ u16 Vs[256][36];       // 18 KB (pad 32->36: bank stride 18)
  const int tid = threadIdx.x, lane = tid & 63, wid = tid >> 6;
  const int g = lane >> 4, lr = lane & 15;
  const int bidx = blockIdx.x / 170, t = blockIdx.x - bidx * 170;
  const int row0 = blockIdx.x * 32;

  // ---- stage A tile (32 x 256) fp32 -> bf16, swizzled ----
  for (int ch = tid; ch < 1024; ch += 512) {
    const int r = ch >> 5, c8 = (ch & 31) * 8;
    const float* ap = A + (size_t)(row0 + r) * 256 + c8;
    const float4 f0 = *(const float4*)ap;
    const float4 f1 = *(const float4*)(ap + 4);
    uint4 pk;
    pk.x = cvtpk(f0.x, f0.y);
    pk.y = cvtpk(f0.z, f0.w);
    pk.z = cvtpk(f1.x, f1.y);
    pk.w = cvtpk(f1.z, f1.w);
    const int byte = r * 512 + c8 * 2;
    *(uint4*)((char*)As + (byte ^ ((r & 7) << 4))) = pk;
  }
  __syncthreads();

  const u16* wbase = Wf + (size_t)wid * 8 * 4 * 512 + lane * 8;
  f32x4 acc[2][4] = {};
#pragma unroll
  for (int ks = 0; ks < 8; ++ks) {
    bf16x8 bfv[4], af[2];
#pragma unroll
    for (int nt = 0; nt < 4; ++nt)
      bfv[nt] = *(const bf16x8*)(wbase + (ks * 4 + nt) * 512);
#pragma unroll
    for (int mt = 0; mt < 2; ++mt) {
      const int r = mt * 16 + lr;
      const int byte = r * 512 + ks * 64 + g * 16;
      af[mt] = *(const bf16x8*)((const char*)As + (byte ^ ((r & 7) << 4)));
    }
#pragma unroll
    for (int mt = 0; mt < 2; ++mt)
#pragma unroll
      for (int nt = 0; nt < 4; ++nt)
        acc[mt][nt] = __builtin_amdgcn_mfma_f32_16x16x32_bf16(af[mt], bfv[nt], acc[mt][nt], 0, 0, 0);
  }

  const int isV = wid >> 2;
  // ---- V assembly (paired u32 writes), no barrier needed before it ----
  if (isV) {
#pragma unroll
    for (int nt = 0; nt < 4; ++nt) {
      const int col = (wid - 4) * 64 + nt * 16 + lr;
      const float bv = biasKV[256 + col];
#pragma unroll
      for (int mt = 0; mt < 2; ++mt) {
        const int slotbase = 16 * mt + 8 * (g & 1) + 4 * (g >> 1);
#pragma unroll
        for (int r = 0; r < 4; r += 2) {
          const u32 val = cvtpk(acc[mt][nt][r] + bv, acc[mt][nt][r + 1] + bv);
          *(u32*)&Vs[col][slotbase + r] = val;
        }
      }
    }
  }
  __syncthreads();   // As K-loop reads done everywhere + Vs complete

  if (!isV) {
    // ---- K assembly into As ----
#pragma unroll
    for (int nt = 0; nt < 4; ++nt) {
      const int col = wid * 64 + nt * 16 + lr;
      const float bv = biasKV[col];
#pragma unroll
      for (int mt = 0; mt < 2; ++mt)
#pragma unroll
        for (int r = 0; r < 4; r += 2) {
          const u32 pk = cvtpk(acc[mt][nt][r] + bv, acc[mt][nt][r + 1] + bv);
          const int rowA = mt * 16 + g * 4 + r;
          const int rowB = rowA + 1;
          *(u16*)((char*)As + ((rowA * 512 + col * 2) ^ ((rowA & 7) << 4))) = (u16)pk;
          *(u16*)((char*)As + ((rowB * 512 + col * 2) ^ ((rowB & 7) << 4))) = (u16)(pk >> 16);
        }
    }
  } else {
    // ---- coop V store (wid4-7, 256 threads, 8B chunks) ----
    const size_t vbase = (size_t)bidx * 256 * 5440 + (size_t)t * 32;
    const int t2 = tid - 256;
#pragma unroll
    for (int p = 0; p < 8; ++p) {
      const int idx = p * 256 + t2;
      const int col = idx >> 3, chunk = idx & 7;
      const uint2 v = *(const uint2*)&Vs[col][chunk * 4];
      *(uint2*)(Vt + vbase + (size_t)col * 5440 + chunk * 4) = v;
    }
  }
  __syncthreads();
  // ---- coop K store (all 512, 2 x uint4 each) ----
#pragma unroll
  for (int p = 0; p < 2; ++p) {
    const int idx = p * 512 + tid;
    const int row = idx >> 5, c16 = idx & 31;
    const int lbyte = row * 512 + ((c16 * 16) ^ ((row & 7) << 4));
    const uint4 v = *(const uint4*)((const char*)As + lbyte);
    *(uint4*)(Kb + (size_t)(row0 + row) * 256 + c16 * 8) = v;
  }
}

// ---------------- Cross-attention: swapped-QK 32x32, register softmax ---------
// S^T = mfma_32x32x16(A=K, B=Q^T): lane holds col q=lane&31, 16 m-rows in regs
// (m = (reg&3)+8*(reg>>2)+4*(lane>>5)). Softmax per-lane + 1 shfl. P feeds PV's
// B operand directly; V^T pre-permuted (see kv_gemm). No LDS.
__global__ __launch_bounds__(256, 3)
void cross_attn_kernel(const u16* __restrict__ Q, const u16* __restrict__ Kb,
                       const u16* __restrict__ Vt, const uint4* __restrict__ biasT5,
                       u32* __restrict__ Opp, float* __restrict__ ML)
{
  const int tid = threadIdx.x, lane = tid & 63, wid = tid >> 6;
  const int ql = lane & 31, hh = lane >> 5;
  const int b = blockIdx.y, c = blockIdx.x;
  const int head = blockIdx.z * 4 + wid;
  const int m_base = c * (5440 / NCH);

  bf16x8 qf[4][2];
#pragma unroll
  for (int qb = 0; qb < 4; ++qb) {
    const int q = qb * 32 + ql;
#pragma unroll
    for (int hf = 0; hf < 2; ++hf)
      qf[qb][hf] = (q < 100)
        ? *(const bf16x8*)&Q[(size_t)(b * 100 + q) * 256 + head * 32 + hf * 16 + hh * 8]
        : zero8();
  }
  float M[4], L[4];
  f32x16 O[4];
#pragma unroll
  for (int qb = 0; qb < 4; ++qb) {
    M[qb] = -1e30f; L[qb] = 0.f;
#pragma unroll
    for (int i = 0; i < 16; ++i) O[qb][i] = 0.f;
  }

  for (int s = 0; s < NSTEP; ++s) {
    const int m0 = m_base + s * 32;
    const u16* kp = &Kb[(size_t)(b * 5440 + m0 + ql) * 256 + head * 32 + hh * 8];
    const bf16x8 kf0 = *(const bf16x8*)kp;
    const bf16x8 kf1 = *(const bf16x8*)(kp + 16);
    const u16* vp = &Vt[((size_t)(b * 8 + head) * 32 + ql) * 5440 + m0 + hh * 8];
    const bf16x8 vf0 = *(const bf16x8*)vp;
    const bf16x8 vf1 = *(const bf16x8*)(vp + 16);
    const uint4* bb = biasT5 + ((size_t)(b * 170 + c * NSTEP + s) * 4) * 128 + lane;
#pragma unroll
    for (int qb = 0; qb < 4; ++qb) {
      const uint4 b0 = bb[qb * 128];
      const uint4 b1 = bb[qb * 128 + 64];
      f32x16 Sv = {};
      __builtin_amdgcn_s_setprio(1);
      Sv = __builtin_amdgcn_mfma_f32_32x32x16_bf16(kf0, qf[qb][0], Sv, 0, 0, 0);
      Sv = __builtin_amdgcn_mfma_f32_32x32x16_bf16(kf1, qf[qb][1], Sv, 0, 0, 0);
      __builtin_amdgcn_s_setprio(0);
      const u32 bw[8] = {b0.x, b0.y, b0.z, b0.w, b1.x, b1.y, b1.z, b1.w};
#pragma unroll
      for (int i = 0; i < 8; ++i) {
        Sv[2 * i]     += b2f((u16)bw[i]);
        Sv[2 * i + 1] += b2f((u16)(bw[i] >> 16));
      }
      // max over 16 in-lane (tree) + partner half
      float t8[8];
#pragma unroll
      for (int i = 0; i < 8; ++i) t8[i] = fmaxf(Sv[2 * i], Sv[2 * i + 1]);
      float t4a = fmaxf(fmaxf(t8[0], t8[1]), fmaxf(t8[2], t8[3]));
      float t4b = fmaxf(fmaxf(t8[4], t8[5]), fmaxf(t8[6], t8[7]));
      float mx = fmaxf(t4a, t4b);
      mx = fmaxf(mx, __shfl_xor(mx, 32));
      const float newM = fmaxf(M[qb], mx);
      const float al = __expf(M[qb] - newM);
      M[qb] = newM;
      float p[16];
#pragma unroll
      for (int i = 0; i < 16; ++i) p[i] = __expf(Sv[i] - newM);
      float s8[8];
#pragma unroll
      for (int i = 0; i < 8; ++i) s8[i] = p[2 * i] + p[2 * i + 1];
      const float sum = ((s8[0] + s8[1]) + (s8[2] + s8[3])) + ((s8[4] + s8[5]) + (s8[6] + s8[7]));
      L[qb] = L[qb] * al + sum;
#pragma unroll
      for (int i = 0; i < 16; ++i) O[qb][i] *= al;
      union { uint4 u; bf16x8 v; } pb0, pb1;
      pb0.u.x = cvtpk(p[0], p[1]);   pb0.u.y = cvtpk(p[2], p[3]);
      pb0.u.z = cvtpk(p[4], p[5]);   pb0.u.w = cvtpk(p[6], p[7]);
      pb1.u.x = cvtpk(p[8], p[9]);   pb1.u.y = cvtpk(p[10], p[11]);
      pb1.u.z = cvtpk(p[12], p[13]); pb1.u.w = cvtpk(p[14], p[15]);
      __builtin_amdgcn_s_setprio(1);
      O[qb] = __builtin_amdgcn_mfma_f32_32x32x16_bf16(vf0, pb0.v, O[qb], 0, 0, 0);
      O[qb] = __builtin_amdgcn_mfma_f32_32x32x16_bf16(vf1, pb1.v, O[qb], 0, 0, 0);
      __builtin_amdgcn_s_setprio(0);
    }
  }
  const int bh = b * 8 + head;
#pragma unroll
  for (int qb = 0; qb < 4; ++qb) {
    const int q = qb * 32 + ql;
    const float Lt = L[qb] + __shfl_xor(L[qb], 32);
    if (q < 100) {
      const size_t rb = (size_t)(bh * NCH + c) * 128 + q;
#pragma unroll
      for (int i = 0; i < 8; ++i)
        Opp[rb * 16 + hh * 8 + i] = cvtpk(O[qb][2 * i], O[qb][2 * i + 1]);
      if (hh == 0) { ML[rb * 2] = M[qb]; ML[rb * 2 + 1] = Lt; }
    }
  }
}

// ---------------- Combine cross-attn partials -> attn_out bf16 [1600,256] ------
// decode: output d -> reg = (d&3)+4*(d>>3), hh = (d>>2)&1, slot = hh*8+(reg>>1)
__global__ __launch_bounds__(256)
void reduce_attn_kernel(const u32* __restrict__ Opp, const float* __restrict__ ML,
                        u16* __restrict__ outb)
{
  const int row = blockIdx.x;            // 0..1599
  const int b = row / 100, q = row % 100;
  const int h = threadIdx.x >> 5, d = threadIdx.x & 31;
  const int bh = b * 8 + h;
  const int reg = (d & 3) + 4 * (d >> 3);
  const int slot = ((d >> 2) & 1) * 8 + (reg >> 1);
  const int half = reg & 1;
  float gm = -1e30f;
  for (int c = 0; c < NCH; ++c) gm = fmaxf(gm, ML[((size_t)(bh * NCH + c) * 128 + q) * 2]);
  float l = 0.f, o = 0.f;
  for (int c = 0; c < NCH; ++c) {
    const size_t rb = (size_t)(bh * NCH + c) * 128 + q;
    const float w = __expf(ML[rb * 2] - gm);
    l += ML[rb * 2 + 1] * w;
    const u32 pv = Opp[rb * 16 + slot];
    o += b2f((u16)(half ? (pv >> 16) : pv)) * w;
  }
  outb[(size_t)row * 256 + h * 32 + d] = f2b(o / l);
}

// ---------------- Self-attention (NQ=100, tiny) ----------------
__global__ __launch_bounds__(128)
void self_attn_kernel(const float* __restrict__ qk, const float* __restrict__ vs,
                      u16* __restrict__ so)
{
  __shared__ u16 kk[100][36];
  __shared__ u16 vv[100][36];
  __shared__ float S[100][101];
  const int b = blockIdx.x >> 3, h = blockIdx.x & 7;
  const int t = threadIdx.x;
  for (int e = t; e < 3200; e += 128) {
    const int r = e >> 5, cq = e & 31;
    kk[r][cq] = f2b(qk[(size_t)(b * 100 + r) * 512 + 256 + h * 32 + cq]);
    vv[r][cq] = f2b(vs[(size_t)(b * 100 + r) * 256 + h * 32 + cq]);
  }
  __syncthreads();
  if (t < 100) {
    float qr_[32];
#pragma unroll
    for (int cq = 0; cq < 32; ++cq) qr_[cq] = qk[(size_t)(b * 100 + t) * 512 + h * 32 + cq];
    for (int m = 0; m < 100; ++m) {
      float dp = 0.f;
#pragma unroll
      for (int cq = 0; cq < 32; ++cq) dp += qr_[cq] * b2f(kk[m][cq]);
      S[t][m] = dp * 0.17677669529663687f;
    }
    float mx = -1e30f;
    for (int m = 0; m < 100; ++m) mx = fmaxf(mx, S[t][m]);
    float sum = 0.f;
    for (int m = 0; m < 100; ++m) { const float p = __expf(S[t][m] - mx); S[t][m] = p; sum += p; }
    const float inv = 1.f / sum;
    float o[32];
#pragma unroll
    for (int cq = 0; cq < 32; ++cq) o[cq] = 0.f;
    for (int m = 0; m < 100; ++m) {
      const float p = S[t][m];
#pragma unroll
      for (int cq = 0; cq < 32; ++cq) o[cq] += p * b2f(vv[m][cq]);
    }
#pragma unroll
    for (int cq = 0; cq < 32; ++cq)
      so[(size_t)(b * 100 + t) * 256 + h * 32 + cq] = f2b(o[cq] * inv);
  }
}

// ---------------- mask_logits: per-b [100,256] @ hr[b][4096,256]^T -------------
__global__ __launch_bounds__(256)
void mask_gemm_kernel(const u16* __restrict__ tm, const float* __restrict__ hr,
                      float* __restrict__ out)
{
  __shared__ u16 As[112][40];
  __shared__ u16 Bs[64][40];
  const int tid = threadIdx.x, lane = tid & 63, wid = tid >> 6;
  const int g = lane >> 4, lr = lane & 15;
  const int b = blockIdx.y, n0 = blockIdx.x * 64;
  f32x4 acc[7] = {};
  for (int k0 = 0; k0 < 256; k0 += 32) {
    for (int cid = tid; cid < 448; cid += 256) {
      const int r = cid >> 2, cg = (cid & 3) * 8;
      uint4 val = {0u, 0u, 0u, 0u};
      if (r < 100) val = *(const uint4*)&tm[(size_t)(b * 100 + r) * 256 + k0 + cg];
      *(uint4*)&As[r][cg] = val;
    }
    {
      const int r = tid >> 2, cg = (tid & 3) * 8;
      const float* hp = hr + (size_t)(b * 4096 + n0 + r) * 256 + k0 + cg;
      float4 f0 = *(const float4*)hp;
      float4 f1 = *(const float4*)(hp + 4);
      uint4 pk;
      pk.x = cvtpk(f0.x, f0.y); pk.y = cvtpk(f0.z, f0.w);
      pk.z = cvtpk(f1.x, f1.y); pk.w = cvtpk(f1.z, f1.w);
      *(uint4*)&Bs[r][cg] = pk;
    }
    __syncthreads();
    const bf16x8 bfr = *(const bf16x8*)&Bs[wid * 16 + lr][g * 8];
#pragma unroll
    for (int mt = 0; mt < 7; ++mt) {
      const bf16x8 af = *(const bf16x8*)&As[mt * 16 + lr][g * 8];
      acc[mt] = __builtin_amdgcn_mfma_f32_16x16x32_bf16(af, bfr, acc[mt], 0, 0, 0);
    }
    __syncthreads();
  }
#pragma unroll
  for (int mt = 0; mt < 7; ++mt)
#pragma unroll
    for (int r = 0; r < 4; ++r) {
      const int qr = mt * 16 + g * 4 + r;
      if (qr < 100)
        out[(size_t)(b * 100 + qr) * 4096 + n0 + wid * 16 + lr] = acc[mt][r];
    }
}

// =======================================================================
extern "C" void kernel_launch(void* const* d_in, const int* in_sizes, int n_in,
                              void* d_out, int out_size, void* d_ws, size_t ws_size,
                              hipStream_t stream)
{
  (void)in_sizes; (void)n_in; (void)out_size; (void)ws_size;
  const float* tgt      = (const float*)d_in[0];
  const float* memory   = (const float*)d_in[1];
  const float* memhr    = (const float*)d_in[2];
  const float* pbias    = (const float*)d_in[3];
  const float* qpos     = (const float*)d_in[4];
  const float* lncw     = (const float*)d_in[5];
  const float* lncb     = (const float*)d_in[6];
  const float* q_w      = (const float*)d_in[7];
  const float* q_b      = (const float*)d_in[8];
  const float* k_w      = (const float*)d_in[9];
  const float* k_b      = (const float*)d_in[10];
  const float* v_w      = (const float*)d_in[11];
  const float* v_b      = (const float*)d_in[12];
  const float* out_w    = (const float*)d_in[13];
  const float* out_b    = (const float*)d_in[14];
  const float* lnsw     = (const float*)d_in[15];
  const float* lnsb     = (const float*)d_in[16];
  const float* sa_in_w  = (const float*)d_in[17];
  const float* sa_in_b  = (const float*)d_in[18];
  const float* sa_out_w = (const float*)d_in[19];
  const float* sa_out_b = (const float*)d_in[20];
  const float* lnfw     = (const float*)d_in[21];
  const float* lnfb     = (const float*)d_in[22];
  const float* l1w      = (const float*)d_in[23];
  const float* l1b      = (const float*)d_in[24];
  const float* l2w      = (const float*)d_in[25];
  const float* l2b      = (const float*)d_in[26];
  const float* me_w     = (const float*)d_in[27];
  const float* me_b     = (const float*)d_in[28];
  float* outf = (float*)d_out;

  char* ws = (char*)d_ws;
  size_t off = 0;
  auto alloc = [&](size_t bytes) -> void* {
    void* p = ws + off;
    off = (off + bytes + 255) & ~(size_t)255;
    return p;
  };
  u16*   Wf    = (u16*)alloc((size_t)131072 * 2);
  u16*   qW    = (u16*)alloc((size_t)65536 * 2);
  u16*   outW  = (u16*)alloc((size_t)65536 * 2);
  u16*   saW   = (u16*)alloc((size_t)196608 * 2);
  u16*   saoW  = (u16*)alloc((size_t)65536 * 2);
  u16*   l1W   = (u16*)alloc((size_t)524288 * 2);
  u16*   l2W   = (u16*)alloc((size_t)524288 * 2);
  u16*   meW   = (u16*)alloc((size_t)65536 * 2);
  float* kvB   = (float*)alloc((size_t)512 * 4);
  uint4* biasT5= (uint4*)alloc((size_t)16 * 170 * 4 * 128 * 16);
  u16*   Qb    = (u16*)alloc((size_t)409600 * 2);
  u16*   Kb    = (u16*)alloc((size_t)22282240 * 2);
  u16*   Vt    = (u16*)alloc((size_t)22282240 * 2);
  u32*   Opp   = (u32*)alloc((size_t)(128 * NCH * 128 * 16) * 4);
  float* MLp   = (float*)alloc((size_t)(128 * NCH * 128 * 2) * 4);
  u16*   attno = (u16*)alloc((size_t)409600 * 2);
  float* tgt1  = (float*)alloc((size_t)409600 * 4);
  float* qkb   = (float*)alloc((size_t)819200 * 4);
  float* vsb   = (float*)alloc((size_t)409600 * 4);
  u16*   sob   = (u16*)alloc((size_t)409600 * 2);
  float* tgt2  = (float*)alloc((size_t)409600 * 4);
  u16*   hb    = (u16*)alloc((size_t)3276800 * 2);
  u16*   t3b   = (u16*)alloc((size_t)409600 * 2);
  u16*   tmb   = (u16*)alloc((size_t)409600 * 2);

  const float SCALE = 0.17677669529663687f;  // 32^-0.5

  // ---- single prep launch ----
  PrepArgs pa;
  pa.seg[0] = {q_w,      qW,   16384};
  pa.seg[1] = {out_w,    outW, 16384};
  pa.seg[2] = {sa_in_w,  saW,  49152};
  pa.seg[3] = {sa_out_w, saoW, 16384};
  pa.seg[4] = {l1w,      l1W,  131072};
  pa.seg[5] = {l2w,      l2W,  131072};
  pa.seg[6] = {me_w,     meW,  16384};
  pa.k_w = k_w; pa.v_w = v_w; pa.k_b = k_b; pa.v_b = v_b; pa.pbias = pbias;
  pa.Wf = Wf; pa.biasT5 = biasT5; pa.kvB = kvB;
  prep_kernel<<<4258, 256, 0, stream>>>(pa);

  // ---- cross attention ----
  qproj_kernel<<<dim3(100, 2), 256, 0, stream>>>(tgt, lncw, lncb, qpos, qW, q_b, Qb, SCALE);
  kv_gemm_kernel<<<dim3(2720), 512, 0, stream>>>(memory, Wf, kvB, Kb, Vt);
  cross_attn_kernel<<<dim3(NCH, 16, 2), 256, 0, stream>>>(Qb, Kb, Vt, biasT5, Opp, MLp);
  reduce_attn_kernel<<<1600, 256, 0, stream>>>(Opp, MLp, attno);
  gemm_kernel<16, 128, 1, 4, 0, 1, 1, 0><<<dim3(100, 2), 256, 0, stream>>>(
      attno, outW, out_b, tgt, tgt1, nullptr, 1600, 256, 256, 1.f);

  // ---- self attention ----
  sain_kernel<<<dim3(100, 6), 256, 0, stream>>>(tgt1, lnsw, lnsb, qpos, saW, sa_in_b, qkb, vsb);
  self_attn_kernel<<<128, 128, 0, stream>>>(qkb, vsb, sob);
  gemm_kernel<16, 128, 1, 4, 0, 1, 1, 0><<<dim3(100, 2), 256, 0, stream>>>(
      sob, saoW, sa_out_b, tgt1, tgt2, nullptr, 1600, 256, 256, 1.f);

  // ---- FFN ----
  ffn1_kernel<<<dim3(25, 8), 256, 0, stream>>>(tgt2, lnfw, lnfb, l1W, l1b, hb);
  gemm_kernel<16, 128, 1, 4, 0, 1, 1, 1><<<dim3(100, 2), 256, 0, stream>>>(
      hb, l2W, l2b, tgt2, outf, t3b, 1600, 256, 2048, 1.f);

  // ---- mask branch ----
  gemm_kernel<16, 128, 1, 4, 0, 0, 0, 1><<<dim3(100, 2), 256, 0, stream>>>(
      t3b, meW, me_b, nullptr, nullptr, tmb, 1600, 256, 256, 1.f);
  mask_gemm_kernel<<<dim3(64, 16), 256, 0, stream>>>(tmb, memhr, outf + 409600);
}

// Round 13
// 326.521 us; speedup vs baseline: 1.1925x; 1.0462x over previous
//
#include <hip/hip_runtime.h>

typedef unsigned short u16;
typedef unsigned int u32;
typedef __bf16 bf16x8 __attribute__((ext_vector_type(8)));
typedef float f32x4 __attribute__((ext_vector_type(4)));
typedef float f32x16 __attribute__((ext_vector_type(16)));

#define NCH 17   // cross-attn split-K chunks (m-chunk = 320, 10 steps of 32)
#define NSTEP 10

__device__ __forceinline__ u16 f2b(float f) {
  u32 u = __float_as_uint(f);
  u32 r = (u + 0x7fffu + ((u >> 16) & 1u)) >> 16;   // RNE, inputs finite
  return (u16)r;
}
__device__ __forceinline__ float b2f(u16 h) {
  return __uint_as_float(((u32)h) << 16);
}
__device__ __forceinline__ bf16x8 zero8() {
  union { uint4 u; bf16x8 v; } z; z.u = make_uint4(0u, 0u, 0u, 0u); return z.v;
}
__device__ __forceinline__ u32 cvtpk(float lo, float hi) {
  u32 r;
  asm("v_cvt_pk_bf16_f32 %0, %1, %2" : "=v"(r) : "v"(lo), "v"(hi));
  return r;
}

// ================= PREP: weight cvt + Wf pack + bias pack + bias repack =======
struct Seg { const float* in; u16* out; int n4; };
struct PrepArgs {
  Seg seg[7];
  const float *k_w, *v_w, *k_b, *v_b, *pbias;
  u16 *Wf;
  uint4 *biasT5;
  float *kvB;
};

// grid: [0,1472) f2b | [1472,1536) Wf pack | [1536,1538) kv bias | [1538,4258) bias repack
__global__ __launch_bounds__(256)
void prep_kernel(PrepArgs a)
{
  __shared__ float S[100][34];
  const int bx = blockIdx.x, tid = threadIdx.x;
  if (bx < 1472) {
    int bxr = bx;
#pragma unroll
    for (int k = 0; k < 7; ++k) {
      const int nb = a.seg[k].n4 >> 8;
      if (bxr < nb) {
        const int i = bxr * 256 + tid;
        const float4 f = *(const float4*)(a.seg[k].in + (size_t)i * 4);
        uint2 pk; pk.x = cvtpk(f.x, f.y); pk.y = cvtpk(f.z, f.w);
        *(uint2*)(a.seg[k].out + (size_t)i * 4) = pk;
        return;
      }
      bxr -= nb;
    }
    return;
  } else if (bx < 1536) {
    // fragment-major pack: Wf[((gI*8+ks)*4+nt)*512 + lane*8 + j]
    const int i = bx - 1472, gI = i >> 3, ks = i & 7;
    const int nt = tid >> 6, lane = tid & 63, lr = lane & 15, g = lane >> 4;
    const float* src = (gI < 4 ? a.k_w + (size_t)(gI * 64 + nt * 16 + lr) * 256
                               : a.v_w + (size_t)((gI - 4) * 64 + nt * 16 + lr) * 256)
                       + ks * 32 + g * 8;
    const float4 f0 = *(const float4*)src;
    const float4 f1 = *(const float4*)(src + 4);
    uint4 pk;
    pk.x = cvtpk(f0.x, f0.y); pk.y = cvtpk(f0.z, f0.w);
    pk.z = cvtpk(f1.x, f1.y); pk.w = cvtpk(f1.z, f1.w);
    *(uint4*)(a.Wf + (size_t)((gI * 8 + ks) * 4 + nt) * 512 + lane * 8) = pk;
  } else if (bx < 1538) {
    const int i = (bx - 1536) * 256 + tid;
    a.kvB[i] = (i < 256) ? a.k_b[i] : a.v_b[i - 256];
  } else {
    // bias repack for swapped-QK: biasT5[bt][qb][half][lane] uint4 (bt = b*170+sg)
    // lane (q = qb*32 + lane&31, hh = lane>>5) holds 16 bf16 in S-reg order:
    //   reg = half*8+i -> m = (reg&3) + 8*(reg>>2) + 4*hh
    const int bt = bx - 1538;          // 0..2719
    const int b = bt / 170, sg = bt - b * 170;
    const int m0 = sg * 32;
    for (int idx = tid; idx < 800; idx += 256) {
      const int q = idx >> 3, seg = idx & 7;
      const float4 v = *(const float4*)(a.pbias + (size_t)(b * 100 + q) * 5440 + m0 + seg * 4);
      S[q][seg * 4 + 0] = v.x; S[q][seg * 4 + 1] = v.y;
      S[q][seg * 4 + 2] = v.z; S[q][seg * 4 + 3] = v.w;
    }
    __syncthreads();
#pragma unroll
    for (int pass = 0; pass < 2; ++pass) {
      const int idx = pass * 256 + tid;
      const int qb = idx >> 7, r2 = idx & 127;
      const int half = r2 >> 6, lane = r2 & 63;
      const int q = qb * 32 + (lane & 31), hh = lane >> 5;
      u16 hv[8];
#pragma unroll
      for (int i = 0; i < 8; ++i) {
        const int reg = half * 8 + i;
        const int m = (reg & 3) + 8 * (reg >> 2) + 4 * hh;
        hv[i] = (q < 100) ? f2b(S[q][m]) : (u16)0;
      }
      uint4 pk;
      pk.x = (u32)hv[0] | ((u32)hv[1] << 16);
      pk.y = (u32)hv[2] | ((u32)hv[3] << 16);
      pk.z = (u32)hv[4] | ((u32)hv[5] << 16);
      pk.w = (u32)hv[6] | ((u32)hv[7] << 16);
      a.biasT5[((size_t)(bt * 4 + qb)) * 128 + half * 64 + lane] = pk;
    }
  }
}

// ---------------- LN staging into swizzled bf16 LDS tile [ROWS][256] ----------
template<int ROWS>
__device__ __forceinline__ void ln_stage(const float* __restrict__ x, int row0,
    const float* __restrict__ w, const float* __restrict__ b,
    const float* __restrict__ pos, u16* As)
{
  const int tid = threadIdx.x, lane = tid & 63, wid = tid >> 6;
  const float4 wv = *(const float4*)(w + lane * 4);
  const float4 bv = *(const float4*)(b + lane * 4);
#pragma unroll
  for (int rr = 0; rr < ROWS / 4; ++rr) {
    const int rl = wid * (ROWS / 4) + rr;
    const size_t o = (size_t)(row0 + rl) * 256 + lane * 4;
    const float4 v = *(const float4*)(x + o);
    float s = v.x + v.y + v.z + v.w;
#pragma unroll
    for (int m = 1; m < 64; m <<= 1) s += __shfl_xor(s, m);
    const float mean = s * (1.f / 256.f);
    const float d0 = v.x - mean, d1 = v.y - mean, d2 = v.z - mean, d3 = v.w - mean;
    float ss = d0 * d0 + d1 * d1 + d2 * d2 + d3 * d3;
#pragma unroll
    for (int m = 1; m < 64; m <<= 1) ss += __shfl_xor(ss, m);
    const float rs = rsqrtf(ss * (1.f / 256.f) + 1e-5f);
    float y0 = d0 * rs * wv.x + bv.x;
    float y1 = d1 * rs * wv.y + bv.y;
    float y2 = d2 * rs * wv.z + bv.z;
    float y3 = d3 * rs * wv.w + bv.w;
    if (pos) {
      const float4 pv = *(const float4*)(pos + o);
      y0 += pv.x; y1 += pv.y; y2 += pv.z; y3 += pv.w;
    }
    uint2 pk; pk.x = cvtpk(y0, y1); pk.y = cvtpk(y2, y3);
    const int byte = (rl * 512 + lane * 8) ^ ((rl & 7) << 4);
    *(uint2*)((char*)As + byte) = pk;
  }
}

// 16x128 GEMM loop reading A from full-K swizzled LDS; W staged per k0.
__device__ __forceinline__ void gemm16x128(const u16* As, const u16* __restrict__ W,
                                           u16 (*Ws)[40], f32x4 acc[2])
{
  const int tid = threadIdx.x, lane = tid & 63, wid = tid >> 6;
  const int g = lane >> 4, lr = lane & 15;
  for (int k0 = 0; k0 < 256; k0 += 32) {
    for (int cid = tid; cid < 512; cid += 256) {
      const int r = cid >> 2, cg = (cid & 3) * 8;
      *(uint4*)&Ws[r][cg] = *(const uint4*)(W + (size_t)r * 256 + k0 + cg);
    }
    __syncthreads();
    const int abyte = (lr * 512 + k0 * 2 + g * 16) ^ ((lr & 7) << 4);
    const bf16x8 af = *(const bf16x8*)((const char*)As + abyte);
#pragma unroll
    for (int nt = 0; nt < 2; ++nt) {
      const bf16x8 bfr = *(const bf16x8*)&Ws[wid * 32 + nt * 16 + lr][g * 8];
      acc[nt] = __builtin_amdgcn_mfma_f32_16x16x32_bf16(af, bfr, acc[nt], 0, 0, 0);
    }
    __syncthreads();
  }
}

// ---------------- q-proj fused with LN(tgt)+qpos; out bf16 scaled -------------
__global__ __launch_bounds__(256)
void qproj_kernel(const float* __restrict__ x, const float* __restrict__ lnw,
                  const float* __restrict__ lnb, const float* __restrict__ pos,
                  const u16* __restrict__ W, const float* __restrict__ bias,
                  u16* __restrict__ out, float scale)
{
  __shared__ u16 As[16 * 256];
  __shared__ u16 Ws[128][40];
  const int tid = threadIdx.x, lane = tid & 63, wid = tid >> 6;
  const int g = lane >> 4, lr = lane & 15;
  const int row0 = blockIdx.x * 16, n0 = blockIdx.y * 128;
  ln_stage<16>(x, row0, lnw, lnb, pos, As);
  f32x4 acc[2] = {};
  gemm16x128(As, W + (size_t)n0 * 256, Ws, acc);
#pragma unroll
  for (int nt = 0; nt < 2; ++nt) {
    const int col = n0 + wid * 32 + nt * 16 + lr;
    const float bv = bias[col];
#pragma unroll
    for (int r = 0; r < 4; ++r) {
      const int row = row0 + g * 4 + r;
      out[(size_t)row * 256 + col] = f2b((acc[nt][r] + bv) * scale);
    }
  }
}

// ---------------- sa_in fused: LN(tgt1)(+qpos for qk), N=768 ------------------
__global__ __launch_bounds__(256)
void sain_kernel(const float* __restrict__ x, const float* __restrict__ lnw,
                 const float* __restrict__ lnb, const float* __restrict__ pos,
                 const u16* __restrict__ W, const float* __restrict__ bias,
                 float* __restrict__ qkb, float* __restrict__ vsb)
{
  __shared__ u16 As[16 * 256];
  __shared__ u16 Ws[128][40];
  const int tid = threadIdx.x, lane = tid & 63, wid = tid >> 6;
  const int g = lane >> 4, lr = lane & 15;
  const int row0 = blockIdx.x * 16, y = blockIdx.y;
  ln_stage<16>(x, row0, lnw, lnb, (y < 4) ? pos : nullptr, As);
  f32x4 acc[2] = {};
  gemm16x128(As, W + (size_t)y * 128 * 256, Ws, acc);
#pragma unroll
  for (int nt = 0; nt < 2; ++nt) {
    const int cl = wid * 32 + nt * 16 + lr;
    const float bv = bias[y * 128 + cl];
#pragma unroll
    for (int r = 0; r < 4; ++r) {
      const int row = row0 + g * 4 + r;
      const float v = acc[nt][r] + bv;
      if (y < 4) qkb[(size_t)row * 512 + y * 128 + cl] = v;
      else       vsb[(size_t)row * 256 + (y - 4) * 128 + cl] = v;
    }
  }
}

// ---------------- FFN lin1 fused with LN(tgt2); GELU; out bf16 ---------------
__global__ __launch_bounds__(256)
void ffn1_kernel(const float* __restrict__ x, const float* __restrict__ lnw,
                 const float* __restrict__ lnb, const u16* __restrict__ W,
                 const float* __restrict__ bias, u16* __restrict__ out)
{
  __shared__ u16 As[64 * 256];
  __shared__ u16 Ws[256][40];
  const int tid = threadIdx.x, lane = tid & 63, wid = tid >> 6;
  const int g = lane >> 4, lr = lane & 15;
  const int row0 = blockIdx.x * 64, n0 = blockIdx.y * 256;
  ln_stage<64>(x, row0, lnw, lnb, nullptr, As);
  f32x4 acc[16] = {};
  for (int k0 = 0; k0 < 256; k0 += 32) {
    for (int cid = tid; cid < 1024; cid += 256) {
      const int r = cid >> 2, cg = (cid & 3) * 8;
      *(uint4*)&Ws[r][cg] = *(const uint4*)(W + (size_t)(n0 + r) * 256 + k0 + cg);
    }
    __syncthreads();
    const int arow = wid * 16 + lr;
    const int abyte = (arow * 512 + k0 * 2 + g * 16) ^ ((arow & 7) << 4);
    const bf16x8 af = *(const bf16x8*)((const char*)As + abyte);
#pragma unroll
    for (int nt = 0; nt < 16; ++nt) {
      const bf16x8 bfr = *(const bf16x8*)&Ws[nt * 16 + lr][g * 8];
      acc[nt] = __builtin_amdgcn_mfma_f32_16x16x32_bf16(af, bfr, acc[nt], 0, 0, 0);
    }
    __syncthreads();
  }
#pragma unroll
  for (int nt = 0; nt < 16; ++nt) {
    const int col = n0 + nt * 16 + lr;
    const float bv = bias[col];
#pragma unroll
    for (int r = 0; r < 4; ++r) {
      const int row = row0 + wid * 16 + g * 4 + r;
      float v = acc[nt][r] + bv;
      v = 0.5f * v * (1.f + erff(v * 0.70710678118654752f));
      out[(size_t)row * 2048 + col] = f2b(v);
    }
  }
}

// ---------------- Generic GEMM: C[M,N] = A[M,K] @ W[N,K]^T + bias -------------
template<int BM, int BN, int WM, int WN, int GELU_, int RES_, int OF32, int OBF>
__global__ __launch_bounds__(256)
void gemm_kernel(const u16* __restrict__ Ap, const u16* __restrict__ W,
                 const float* __restrict__ bias, const float* __restrict__ res,
                 float* __restrict__ Cf, u16* __restrict__ Cb,
                 int M, int N, int K, float scale)
{
  constexpr int WROWS = BM / WM;
  constexpr int WCOLS = BN / WN;
  constexpr int MT = WROWS / 16;
  constexpr int NT = WCOLS / 16;
  static_assert(WM * WN == 4, "4 waves");
  __shared__ u16 As[BM][40];
  __shared__ u16 Ws[BN][40];
  const int tid = threadIdx.x, lane = tid & 63, wid = tid >> 6;
  const int g = lane >> 4, lr = lane & 15;
  const int m0 = blockIdx.x * BM, n0 = blockIdx.y * BN;
  const int wm = wid / WN, wn = wid % WN;
  f32x4 acc[MT][NT] = {};
  for (int k0 = 0; k0 < K; k0 += 32) {
    for (int cid = tid; cid < BM * 4; cid += 256) {
      int r = cid >> 2, cg = (cid & 3) * 8;
      *(uint4*)&As[r][cg] = *(const uint4*)(Ap + (size_t)(m0 + r) * K + k0 + cg);
    }
    for (int cid = tid; cid < BN * 4; cid += 256) {
      int r = cid >> 2, cg = (cid & 3) * 8;
      *(uint4*)&Ws[r][cg] = *(const uint4*)(W + (size_t)(n0 + r) * K + k0 + cg);
    }
    __syncthreads();
    bf16x8 af[MT], bfr[NT];
#pragma unroll
    for (int mt = 0; mt < MT; ++mt) af[mt] = *(const bf16x8*)&As[wm * WROWS + mt * 16 + lr][g * 8];
#pragma unroll
    for (int nt = 0; nt < NT; ++nt) bfr[nt] = *(const bf16x8*)&Ws[wn * WCOLS + nt * 16 + lr][g * 8];
#pragma unroll
    for (int mt = 0; mt < MT; ++mt)
#pragma unroll
      for (int nt = 0; nt < NT; ++nt)
        acc[mt][nt] = __builtin_amdgcn_mfma_f32_16x16x32_bf16(af[mt], bfr[nt], acc[mt][nt], 0, 0, 0);
    __syncthreads();
  }
#pragma unroll
  for (int mt = 0; mt < MT; ++mt)
#pragma unroll
    for (int nt = 0; nt < NT; ++nt) {
      const int col = n0 + wn * WCOLS + nt * 16 + lr;
      const float bv = bias[col];
#pragma unroll
      for (int r = 0; r < 4; ++r) {
        const int row = m0 + wm * WROWS + mt * 16 + g * 4 + r;
        float v = (acc[mt][nt][r] + bv) * scale;
        if constexpr (GELU_) v = 0.5f * v * (1.f + erff(v * 0.70710678118654752f));
        if constexpr (RES_) v += res[(size_t)row * N + col];
        if constexpr (OF32) Cf[(size_t)row * N + col] = v;
        if constexpr (OBF) Cb[(size_t)row * N + col] = f2b(v);
      }
    }
}

// ---------------- KV projection GEMM — BM=64, 3-barrier epilogue --------------
// V permutation within each 32-m block matches the swapped-QK PV k-slot order.
__global__ __launch_bounds__(512, 4)
void kv_gemm_kernel(const float* __restrict__ A, const u16* __restrict__ Wf,
                    const float* __restrict__ biasKV,
                    u16* __restrict__ Kb, u16* __restrict__ Vt)
{
  __shared__ u16 As[64 * 256];
  __shared__ u16 Vs[256 * 64];
  const int tid = threadIdx.x, lane = tid & 63, wid = tid >> 6;
  const int g = lane >> 4, lr = lane & 15;
  const int bidx = blockIdx.x / 85, t = blockIdx.x - bidx * 85;
  const int row0 = blockIdx.x * 64;

  for (int ch = tid; ch < 2048; ch += 512) {
    const int r = ch >> 5, c8 = (ch & 31) * 8;
    const float* ap = A + (size_t)(row0 + r) * 256 + c8;
    const float4 f0 = *(const float4*)ap;
    const float4 f1 = *(const float4*)(ap + 4);
    uint4 pk;
    pk.x = cvtpk(f0.x, f0.y);
    pk.y = cvtpk(f0.z, f0.w);
    pk.z = cvtpk(f1.x, f1.y);
    pk.w = cvtpk(f1.z, f1.w);
    const int byte = r * 512 + c8 * 2;
    *(uint4*)((char*)As + (byte ^ ((r & 7) << 4))) = pk;
  }
  __syncthreads();

  const u16* wbase = Wf + (size_t)wid * 8 * 4 * 512 + lane * 8;
  f32x4 acc[4][4] = {};
#pragma unroll 2
  for (int ks = 0; ks < 8; ++ks) {
    bf16x8 bfv[4], af[4];
#pragma unroll
    for (int nt = 0; nt < 4; ++nt)
      bfv[nt] = *(const bf16x8*)(wbase + (ks * 4 + nt) * 512);
#pragma unroll
    for (int mt = 0; mt < 4; ++mt) {
      const int r = mt * 16 + lr;
      const int byte = r * 512 + ks * 64 + g * 16;
      af[mt] = *(const bf16x8*)((const char*)As + (byte ^ ((r & 7) << 4)));
    }
#pragma unroll
    for (int mt = 0; mt < 4; ++mt)
#pragma unroll
      for (int nt = 0; nt < 4; ++nt)
        acc[mt][nt] = __builtin_amdgcn_mfma_f32_16x16x32_bf16(af[mt], bfv[nt], acc[mt][nt], 0, 0, 0);
  }

  const int isV = wid >> 2;
  if (isV) {
#pragma unroll
    for (int nt = 0; nt < 4; ++nt) {
      const int col = (wid - 4) * 64 + nt * 16 + lr;
      const float bv = biasKV[256 + col];
#pragma unroll
      for (int mt = 0; mt < 4; ++mt) {
        const int slot = (mt >> 1) * 32 + 16 * (mt & 1) + 8 * (g & 1) + 4 * (g >> 1);
#pragma unroll
        for (int r = 0; r < 4; r += 2) {
          const u32 val = cvtpk(acc[mt][nt][r] + bv, acc[mt][nt][r + 1] + bv);
          const int byte = (col * 128 + (slot + r) * 2) ^ ((col & 7) << 4);
          *(u32*)((char*)Vs + byte) = val;
        }
      }
    }
  }
  __syncthreads();

  if (!isV) {
#pragma unroll
    for (int nt = 0; nt < 4; ++nt) {
      const int col = wid * 64 + nt * 16 + lr;
      const float bv = biasKV[col];
#pragma unroll
      for (int mt = 0; mt < 4; ++mt)
#pragma unroll
        for (int r = 0; r < 4; r += 2) {
          const u32 pk = cvtpk(acc[mt][nt][r] + bv, acc[mt][nt][r + 1] + bv);
          const int rowA = mt * 16 + g * 4 + r;
          const int rowB = rowA + 1;
          *(u16*)((char*)As + ((rowA * 512 + col * 2) ^ ((rowA & 7) << 4))) = (u16)pk;
          *(u16*)((char*)As + ((rowB * 512 + col * 2) ^ ((rowB & 7) << 4))) = (u16)(pk >> 16);
        }
    }
  } else {
    const size_t vbase = (size_t)bidx * 256 * 5440 + (size_t)t * 64;
    const int t2 = tid - 256;
#pragma unroll
    for (int p = 0; p < 8; ++p) {
      const int idx = p * 256 + t2;
      const int col = idx >> 3, chunk = idx & 7;
      const int lbyte = col * 128 + ((chunk * 16) ^ ((col & 7) << 4));
      const uint4 v = *(const uint4*)((const char*)Vs + lbyte);
      *(uint4*)(Vt + vbase + (size_t)col * 5440 + chunk * 8) = v;
    }
  }
  __syncthreads();
#pragma unroll
  for (int p = 0; p < 4; ++p) {
    const int idx = p * 512 + tid;
    const int row = idx >> 5, c16 = idx & 31;
    const int lbyte = row * 512 + ((c16 * 16) ^ ((row & 7) << 4));
    const uint4 v = *(const uint4*)((const char*)As + lbyte);
    *(uint4*)(Kb + (size_t)(row0 + row) * 256 + c16 * 8) = v;
  }
}

// ---------------- Cross-attention: swapped-QK 32x32, register softmax ---------
// S^T = mfma_32x32x16(A=K, B=Q^T): lane holds col q=lane&31, 16 m-rows in regs
// (m = (reg&3)+8*(reg>>2)+4*(lane>>5)). Softmax per-lane + 1 shfl. P feeds PV's
// B operand directly; V^T pre-permuted (see kv_gemm). No LDS.
__global__ __launch_bounds__(256, 3)
void cross_attn_kernel(const u16* __restrict__ Q, const u16* __restrict__ Kb,
                       const u16* __restrict__ Vt, const uint4* __restrict__ biasT5,
                       u32* __restrict__ Opp, float* __restrict__ ML)
{
  const int tid = threadIdx.x, lane = tid & 63, wid = tid >> 6;
  const int ql = lane & 31, hh = lane >> 5;
  const int b = blockIdx.y, c = blockIdx.x;
  const int head = blockIdx.z * 4 + wid;
  const int m_base = c * (5440 / NCH);

  bf16x8 qf[4][2];
#pragma unroll
  for (int qb = 0; qb < 4; ++qb) {
    const int q = qb * 32 + ql;
#pragma unroll
    for (int hf = 0; hf < 2; ++hf)
      qf[qb][hf] = (q < 100)
        ? *(const bf16x8*)&Q[(size_t)(b * 100 + q) * 256 + head * 32 + hf * 16 + hh * 8]
        : zero8();
  }
  float M[4], L[4];
  f32x16 O[4];
#pragma unroll
  for (int qb = 0; qb < 4; ++qb) {
    M[qb] = -1e30f; L[qb] = 0.f;
#pragma unroll
    for (int i = 0; i < 16; ++i) O[qb][i] = 0.f;
  }

  for (int s = 0; s < NSTEP; ++s) {
    const int m0 = m_base + s * 32;
    const u16* kp = &Kb[(size_t)(b * 5440 + m0 + ql) * 256 + head * 32 + hh * 8];
    const bf16x8 kf0 = *(const bf16x8*)kp;
    const bf16x8 kf1 = *(const bf16x8*)(kp + 16);
    const u16* vp = &Vt[((size_t)(b * 8 + head) * 32 + ql) * 5440 + m0 + hh * 8];
    const bf16x8 vf0 = *(const bf16x8*)vp;
    const bf16x8 vf1 = *(const bf16x8*)(vp + 16);
    const uint4* bb = biasT5 + ((size_t)(b * 170 + c * NSTEP + s) * 4) * 128 + lane;
#pragma unroll
    for (int qb = 0; qb < 4; ++qb) {
      const uint4 b0 = bb[qb * 128];
      const uint4 b1 = bb[qb * 128 + 64];
      f32x16 Sv = {};
      __builtin_amdgcn_s_setprio(1);
      Sv = __builtin_amdgcn_mfma_f32_32x32x16_bf16(kf0, qf[qb][0], Sv, 0, 0, 0);
      Sv = __builtin_amdgcn_mfma_f32_32x32x16_bf16(kf1, qf[qb][1], Sv, 0, 0, 0);
      __builtin_amdgcn_s_setprio(0);
      const u32 bw[8] = {b0.x, b0.y, b0.z, b0.w, b1.x, b1.y, b1.z, b1.w};
#pragma unroll
      for (int i = 0; i < 8; ++i) {
        Sv[2 * i]     += b2f((u16)bw[i]);
        Sv[2 * i + 1] += b2f((u16)(bw[i] >> 16));
      }
      // max over 16 in-lane (tree) + partner half
      float t8[8];
#pragma unroll
      for (int i = 0; i < 8; ++i) t8[i] = fmaxf(Sv[2 * i], Sv[2 * i + 1]);
      float t4a = fmaxf(fmaxf(t8[0], t8[1]), fmaxf(t8[2], t8[3]));
      float t4b = fmaxf(fmaxf(t8[4], t8[5]), fmaxf(t8[6], t8[7]));
      float mx = fmaxf(t4a, t4b);
      mx = fmaxf(mx, __shfl_xor(mx, 32));
      const float newM = fmaxf(M[qb], mx);
      const float al = __expf(M[qb] - newM);
      M[qb] = newM;
      float p[16];
#pragma unroll
      for (int i = 0; i < 16; ++i) p[i] = __expf(Sv[i] - newM);
      float s8[8];
#pragma unroll
      for (int i = 0; i < 8; ++i) s8[i] = p[2 * i] + p[2 * i + 1];
      const float sum = ((s8[0] + s8[1]) + (s8[2] + s8[3])) + ((s8[4] + s8[5]) + (s8[6] + s8[7]));
      L[qb] = L[qb] * al + sum;
#pragma unroll
      for (int i = 0; i < 16; ++i) O[qb][i] *= al;
      union { uint4 u; bf16x8 v; } pb0, pb1;
      pb0.u.x = cvtpk(p[0], p[1]);   pb0.u.y = cvtpk(p[2], p[3]);
      pb0.u.z = cvtpk(p[4], p[5]);   pb0.u.w = cvtpk(p[6], p[7]);
      pb1.u.x = cvtpk(p[8], p[9]);   pb1.u.y = cvtpk(p[10], p[11]);
      pb1.u.z = cvtpk(p[12], p[13]); pb1.u.w = cvtpk(p[14], p[15]);
      __builtin_amdgcn_s_setprio(1);
      O[qb] = __builtin_amdgcn_mfma_f32_32x32x16_bf16(vf0, pb0.v, O[qb], 0, 0, 0);
      O[qb] = __builtin_amdgcn_mfma_f32_32x32x16_bf16(vf1, pb1.v, O[qb], 0, 0, 0);
      __builtin_amdgcn_s_setprio(0);
    }
  }
  const int bh = b * 8 + head;
#pragma unroll
  for (int qb = 0; qb < 4; ++qb) {
    const int q = qb * 32 + ql;
    const float Lt = L[qb] + __shfl_xor(L[qb], 32);
    if (q < 100) {
      const size_t rb = (size_t)(bh * NCH + c) * 128 + q;
#pragma unroll
      for (int i = 0; i < 8; ++i)
        Opp[rb * 16 + hh * 8 + i] = cvtpk(O[qb][2 * i], O[qb][2 * i + 1]);
      if (hh == 0) { ML[rb * 2] = M[qb]; ML[rb * 2 + 1] = Lt; }
    }
  }
}

// ---------------- Combine cross-attn partials -> attn_out bf16 [1600,256] ------
// decode: output d -> reg = (d&3)+4*(d>>3), hh = (d>>2)&1, slot = hh*8+(reg>>1)
__global__ __launch_bounds__(256)
void reduce_attn_kernel(const u32* __restrict__ Opp, const float* __restrict__ ML,
                        u16* __restrict__ outb)
{
  const int row = blockIdx.x;            // 0..1599
  const int b = row / 100, q = row % 100;
  const int h = threadIdx.x >> 5, d = threadIdx.x & 31;
  const int bh = b * 8 + h;
  const int reg = (d & 3) + 4 * (d >> 3);
  const int slot = ((d >> 2) & 1) * 8 + (reg >> 1);
  const int half = reg & 1;
  float gm = -1e30f;
  for (int c = 0; c < NCH; ++c) gm = fmaxf(gm, ML[((size_t)(bh * NCH + c) * 128 + q) * 2]);
  float l = 0.f, o = 0.f;
  for (int c = 0; c < NCH; ++c) {
    const size_t rb = (size_t)(bh * NCH + c) * 128 + q;
    const float w = __expf(ML[rb * 2] - gm);
    l += ML[rb * 2 + 1] * w;
    const u32 pv = Opp[rb * 16 + slot];
    o += b2f((u16)(half ? (pv >> 16) : pv)) * w;
  }
  outb[(size_t)row * 256 + h * 32 + d] = f2b(o / l);
}

// ---------------- Self-attention (NQ=100, tiny) ----------------
__global__ __launch_bounds__(128)
void self_attn_kernel(const float* __restrict__ qk, const float* __restrict__ vs,
                      u16* __restrict__ so)
{
  __shared__ u16 kk[100][36];
  __shared__ u16 vv[100][36];
  __shared__ float S[100][101];
  const int b = blockIdx.x >> 3, h = blockIdx.x & 7;
  const int t = threadIdx.x;
  for (int e = t; e < 3200; e += 128) {
    const int r = e >> 5, cq = e & 31;
    kk[r][cq] = f2b(qk[(size_t)(b * 100 + r) * 512 + 256 + h * 32 + cq]);
    vv[r][cq] = f2b(vs[(size_t)(b * 100 + r) * 256 + h * 32 + cq]);
  }
  __syncthreads();
  if (t < 100) {
    float qr_[32];
#pragma unroll
    for (int cq = 0; cq < 32; ++cq) qr_[cq] = qk[(size_t)(b * 100 + t) * 512 + h * 32 + cq];
    for (int m = 0; m < 100; ++m) {
      float dp = 0.f;
#pragma unroll
      for (int cq = 0; cq < 32; ++cq) dp += qr_[cq] * b2f(kk[m][cq]);
      S[t][m] = dp * 0.17677669529663687f;
    }
    float mx = -1e30f;
    for (int m = 0; m < 100; ++m) mx = fmaxf(mx, S[t][m]);
    float sum = 0.f;
    for (int m = 0; m < 100; ++m) { const float p = __expf(S[t][m] - mx); S[t][m] = p; sum += p; }
    const float inv = 1.f / sum;
    float o[32];
#pragma unroll
    for (int cq = 0; cq < 32; ++cq) o[cq] = 0.f;
    for (int m = 0; m < 100; ++m) {
      const float p = S[t][m];
#pragma unroll
      for (int cq = 0; cq < 32; ++cq) o[cq] += p * b2f(vv[m][cq]);
    }
#pragma unroll
    for (int cq = 0; cq < 32; ++cq)
      so[(size_t)(b * 100 + t) * 256 + h * 32 + cq] = f2b(o[cq] * inv);
  }
}

// ---------------- mask_logits: per-b [100,256] @ hr[b][4096,256]^T -------------
__global__ __launch_bounds__(256)
void mask_gemm_kernel(const u16* __restrict__ tm, const float* __restrict__ hr,
                      float* __restrict__ out)
{
  __shared__ u16 As[112][40];
  __shared__ u16 Bs[64][40];
  const int tid = threadIdx.x, lane = tid & 63, wid = tid >> 6;
  const int g = lane >> 4, lr = lane & 15;
  const int b = blockIdx.y, n0 = blockIdx.x * 64;
  f32x4 acc[7] = {};
  for (int k0 = 0; k0 < 256; k0 += 32) {
    for (int cid = tid; cid < 448; cid += 256) {
      const int r = cid >> 2, cg = (cid & 3) * 8;
      uint4 val = {0u, 0u, 0u, 0u};
      if (r < 100) val = *(const uint4*)&tm[(size_t)(b * 100 + r) * 256 + k0 + cg];
      *(uint4*)&As[r][cg] = val;
    }
    {
      const int r = tid >> 2, cg = (tid & 3) * 8;
      const float* hp = hr + (size_t)(b * 4096 + n0 + r) * 256 + k0 + cg;
      float4 f0 = *(const float4*)hp;
      float4 f1 = *(const float4*)(hp + 4);
      uint4 pk;
      pk.x = cvtpk(f0.x, f0.y); pk.y = cvtpk(f0.z, f0.w);
      pk.z = cvtpk(f1.x, f1.y); pk.w = cvtpk(f1.z, f1.w);
      *(uint4*)&Bs[r][cg] = pk;
    }
    __syncthreads();
    const bf16x8 bfr = *(const bf16x8*)&Bs[wid * 16 + lr][g * 8];
#pragma unroll
    for (int mt = 0; mt < 7; ++mt) {
      const bf16x8 af = *(const bf16x8*)&As[mt * 16 + lr][g * 8];
      acc[mt] = __builtin_amdgcn_mfma_f32_16x16x32_bf16(af, bfr, acc[mt], 0, 0, 0);
    }
    __syncthreads();
  }
#pragma unroll
  for (int mt = 0; mt < 7; ++mt)
#pragma unroll
    for (int r = 0; r < 4; ++r) {
      const int qr = mt * 16 + g * 4 + r;
      if (qr < 100)
        out[(size_t)(b * 100 + qr) * 4096 + n0 + wid * 16 + lr] = acc[mt][r];
    }
}

// =======================================================================
extern "C" void kernel_launch(void* const* d_in, const int* in_sizes, int n_in,
                              void* d_out, int out_size, void* d_ws, size_t ws_size,
                              hipStream_t stream)
{
  (void)in_sizes; (void)n_in; (void)out_size; (void)ws_size;
  const float* tgt      = (const float*)d_in[0];
  const float* memory   = (const float*)d_in[1];
  const float* memhr    = (const float*)d_in[2];
  const float* pbias    = (const float*)d_in[3];
  const float* qpos     = (const float*)d_in[4];
  const float* lncw     = (const float*)d_in[5];
  const float* lncb     = (const float*)d_in[6];
  const float* q_w      = (const float*)d_in[7];
  const float* q_b      = (const float*)d_in[8];
  const float* k_w      = (const float*)d_in[9];
  const float* k_b      = (const float*)d_in[10];
  const float* v_w      = (const float*)d_in[11];
  const float* v_b      = (const float*)d_in[12];
  const float* out_w    = (const float*)d_in[13];
  const float* out_b    = (const float*)d_in[14];
  const float* lnsw     = (const float*)d_in[15];
  const float* lnsb     = (const float*)d_in[16];
  const float* sa_in_w  = (const float*)d_in[17];
  const float* sa_in_b  = (const float*)d_in[18];
  const float* sa_out_w = (const float*)d_in[19];
  const float* sa_out_b = (const float*)d_in[20];
  const float* lnfw     = (const float*)d_in[21];
  const float* lnfb     = (const float*)d_in[22];
  const float* l1w      = (const float*)d_in[23];
  const float* l1b      = (const float*)d_in[24];
  const float* l2w      = (const float*)d_in[25];
  const float* l2b      = (const float*)d_in[26];
  const float* me_w     = (const float*)d_in[27];
  const float* me_b     = (const float*)d_in[28];
  float* outf = (float*)d_out;

  char* ws = (char*)d_ws;
  size_t off = 0;
  auto alloc = [&](size_t bytes) -> void* {
    void* p = ws + off;
    off = (off + bytes + 255) & ~(size_t)255;
    return p;
  };
  u16*   Wf    = (u16*)alloc((size_t)131072 * 2);
  u16*   qW    = (u16*)alloc((size_t)65536 * 2);
  u16*   outW  = (u16*)alloc((size_t)65536 * 2);
  u16*   saW   = (u16*)alloc((size_t)196608 * 2);
  u16*   saoW  = (u16*)alloc((size_t)65536 * 2);
  u16*   l1W   = (u16*)alloc((size_t)524288 * 2);
  u16*   l2W   = (u16*)alloc((size_t)524288 * 2);
  u16*   meW   = (u16*)alloc((size_t)65536 * 2);
  float* kvB   = (float*)alloc((size_t)512 * 4);
  uint4* biasT5= (uint4*)alloc((size_t)16 * 170 * 4 * 128 * 16);
  u16*   Qb    = (u16*)alloc((size_t)409600 * 2);
  u16*   Kb    = (u16*)alloc((size_t)22282240 * 2);
  u16*   Vt    = (u16*)alloc((size_t)22282240 * 2);
  u32*   Opp   = (u32*)alloc((size_t)(128 * NCH * 128 * 16) * 4);
  float* MLp   = (float*)alloc((size_t)(128 * NCH * 128 * 2) * 4);
  u16*   attno = (u16*)alloc((size_t)409600 * 2);
  float* tgt1  = (float*)alloc((size_t)409600 * 4);
  float* qkb   = (float*)alloc((size_t)819200 * 4);
  float* vsb   = (float*)alloc((size_t)409600 * 4);
  u16*   sob   = (u16*)alloc((size_t)409600 * 2);
  float* tgt2  = (float*)alloc((size_t)409600 * 4);
  u16*   hb    = (u16*)alloc((size_t)3276800 * 2);
  u16*   t3b   = (u16*)alloc((size_t)409600 * 2);
  u16*   tmb   = (u16*)alloc((size_t)409600 * 2);

  const float SCALE = 0.17677669529663687f;  // 32^-0.5

  // ---- single prep launch ----
  PrepArgs pa;
  pa.seg[0] = {q_w,      qW,   16384};
  pa.seg[1] = {out_w,    outW, 16384};
  pa.seg[2] = {sa_in_w,  saW,  49152};
  pa.seg[3] = {sa_out_w, saoW, 16384};
  pa.seg[4] = {l1w,      l1W,  131072};
  pa.seg[5] = {l2w,      l2W,  131072};
  pa.seg[6] = {me_w,     meW,  16384};
  pa.k_w = k_w; pa.v_w = v_w; pa.k_b = k_b; pa.v_b = v_b; pa.pbias = pbias;
  pa.Wf = Wf; pa.biasT5 = biasT5; pa.kvB = kvB;
  prep_kernel<<<4258, 256, 0, stream>>>(pa);

  // ---- cross attention ----
  qproj_kernel<<<dim3(100, 2), 256, 0, stream>>>(tgt, lncw, lncb, qpos, qW, q_b, Qb, SCALE);
  kv_gemm_kernel<<<dim3(1360), 512, 0, stream>>>(memory, Wf, kvB, Kb, Vt);
  cross_attn_kernel<<<dim3(NCH, 16, 2), 256, 0, stream>>>(Qb, Kb, Vt, biasT5, Opp, MLp);
  reduce_attn_kernel<<<1600, 256, 0, stream>>>(Opp, MLp, attno);
  gemm_kernel<16, 128, 1, 4, 0, 1, 1, 0><<<dim3(100, 2), 256, 0, stream>>>(
      attno, outW, out_b, tgt, tgt1, nullptr, 1600, 256, 256, 1.f);

  // ---- self attention ----
  sain_kernel<<<dim3(100, 6), 256, 0, stream>>>(tgt1, lnsw, lnsb, qpos, saW, sa_in_b, qkb, vsb);
  self_attn_kernel<<<128, 128, 0, stream>>>(qkb, vsb, sob);
  gemm_kernel<16, 128, 1, 4, 0, 1, 1, 0><<<dim3(100, 2), 256, 0, stream>>>(
      sob, saoW, sa_out_b, tgt1, tgt2, nullptr, 1600, 256, 256, 1.f);

  // ---- FFN ----
  ffn1_kernel<<<dim3(25, 8), 256, 0, stream>>>(tgt2, lnfw, lnfb, l1W, l1b, hb);
  gemm_kernel<16, 128, 1, 4, 0, 1, 1, 1><<<dim3(100, 2), 256, 0, stream>>>(
      hb, l2W, l2b, tgt2, outf, t3b, 1600, 256, 2048, 1.f);

  // ---- mask branch ----
  gemm_kernel<16, 128, 1, 4, 0, 0, 0, 1><<<dim3(100, 2), 256, 0, stream>>>(
      t3b, meW, me_b, nullptr, nullptr, tmb, 1600, 256, 256, 1.f);
  mask_gemm_kernel<<<dim3(64, 16), 256, 0, stream>>>(tmb, memhr, outf + 409600);
}

// Round 14
// 312.684 us; speedup vs baseline: 1.2453x; 1.0443x over previous
//
#include <hip/hip_runtime.h>

typedef unsigned short u16;
typedef unsigned int u32;
typedef __bf16 bf16x8 __attribute__((ext_vector_type(8)));
typedef float f32x4 __attribute__((ext_vector_type(4)));
typedef float f32x16 __attribute__((ext_vector_type(16)));

#define NCH 17   // cross-attn split-K chunks (m-chunk = 320, 10 steps of 32)
#define NSTEP 10

__device__ __forceinline__ u16 f2b(float f) {
  u32 u = __float_as_uint(f);
  u32 r = (u + 0x7fffu + ((u >> 16) & 1u)) >> 16;   // RNE, inputs finite
  return (u16)r;
}
__device__ __forceinline__ float b2f(u16 h) {
  return __uint_as_float(((u32)h) << 16);
}
__device__ __forceinline__ bf16x8 zero8() {
  union { uint4 u; bf16x8 v; } z; z.u = make_uint4(0u, 0u, 0u, 0u); return z.v;
}
__device__ __forceinline__ u32 cvtpk(float lo, float hi) {
  u32 r;
  asm("v_cvt_pk_bf16_f32 %0, %1, %2" : "=v"(r) : "v"(lo), "v"(hi));
  return r;
}

// ================= PREP: weight cvt + Wf pack + bias pack + bias repack =======
struct Seg { const float* in; u16* out; int n4; };
struct PrepArgs {
  Seg seg[7];
  const float *k_w, *v_w, *k_b, *v_b, *pbias;
  u16 *Wf;
  uint4 *biasT5;
  float *kvB;
};

// grid: [0,1472) f2b | [1472,1536) Wf pack | [1536,1538) kv bias | [1538,4258) bias repack
__global__ __launch_bounds__(256)
void prep_kernel(PrepArgs a)
{
  __shared__ float S[100][34];
  const int bx = blockIdx.x, tid = threadIdx.x;
  if (bx < 1472) {
    int bxr = bx;
#pragma unroll
    for (int k = 0; k < 7; ++k) {
      const int nb = a.seg[k].n4 >> 8;
      if (bxr < nb) {
        const int i = bxr * 256 + tid;
        const float4 f = *(const float4*)(a.seg[k].in + (size_t)i * 4);
        uint2 pk; pk.x = cvtpk(f.x, f.y); pk.y = cvtpk(f.z, f.w);
        *(uint2*)(a.seg[k].out + (size_t)i * 4) = pk;
        return;
      }
      bxr -= nb;
    }
    return;
  } else if (bx < 1536) {
    // fragment-major pack: Wf[((gI*8+ks)*4+nt)*512 + lane*8 + j]
    const int i = bx - 1472, gI = i >> 3, ks = i & 7;
    const int nt = tid >> 6, lane = tid & 63, lr = lane & 15, g = lane >> 4;
    const float* src = (gI < 4 ? a.k_w + (size_t)(gI * 64 + nt * 16 + lr) * 256
                               : a.v_w + (size_t)((gI - 4) * 64 + nt * 16 + lr) * 256)
                       + ks * 32 + g * 8;
    const float4 f0 = *(const float4*)src;
    const float4 f1 = *(const float4*)(src + 4);
    uint4 pk;
    pk.x = cvtpk(f0.x, f0.y); pk.y = cvtpk(f0.z, f0.w);
    pk.z = cvtpk(f1.x, f1.y); pk.w = cvtpk(f1.z, f1.w);
    *(uint4*)(a.Wf + (size_t)((gI * 8 + ks) * 4 + nt) * 512 + lane * 8) = pk;
  } else if (bx < 1538) {
    const int i = (bx - 1536) * 256 + tid;
    a.kvB[i] = (i < 256) ? a.k_b[i] : a.v_b[i - 256];
  } else {
    // bias repack for swapped-QK: biasT5[bt][qb][half][lane] uint4 (bt = b*170+sg)
    // lane (q = qb*32 + lane&31, hh = lane>>5) holds 16 bf16 in S-reg order:
    //   reg = half*8+i -> m = (reg&3) + 8*(reg>>2) + 4*hh
    const int bt = bx - 1538;          // 0..2719
    const int b = bt / 170, sg = bt - b * 170;
    const int m0 = sg * 32;
    for (int idx = tid; idx < 800; idx += 256) {
      const int q = idx >> 3, seg = idx & 7;
      const float4 v = *(const float4*)(a.pbias + (size_t)(b * 100 + q) * 5440 + m0 + seg * 4);
      S[q][seg * 4 + 0] = v.x; S[q][seg * 4 + 1] = v.y;
      S[q][seg * 4 + 2] = v.z; S[q][seg * 4 + 3] = v.w;
    }
    __syncthreads();
#pragma unroll
    for (int pass = 0; pass < 2; ++pass) {
      const int idx = pass * 256 + tid;
      const int qb = idx >> 7, r2 = idx & 127;
      const int half = r2 >> 6, lane = r2 & 63;
      const int q = qb * 32 + (lane & 31), hh = lane >> 5;
      u16 hv[8];
#pragma unroll
      for (int i = 0; i < 8; ++i) {
        const int reg = half * 8 + i;
        const int m = (reg & 3) + 8 * (reg >> 2) + 4 * hh;
        hv[i] = (q < 100) ? f2b(S[q][m]) : (u16)0;
      }
      uint4 pk;
      pk.x = (u32)hv[0] | ((u32)hv[1] << 16);
      pk.y = (u32)hv[2] | ((u32)hv[3] << 16);
      pk.z = (u32)hv[4] | ((u32)hv[5] << 16);
      pk.w = (u32)hv[6] | ((u32)hv[7] << 16);
      a.biasT5[((size_t)(bt * 4 + qb)) * 128 + half * 64 + lane] = pk;
    }
  }
}

// ---------------- LN staging into swizzled bf16 LDS tile [ROWS][256] ----------
template<int ROWS>
__device__ __forceinline__ void ln_stage(const float* __restrict__ x, int row0,
    const float* __restrict__ w, const float* __restrict__ b,
    const float* __restrict__ pos, u16* As)
{
  const int tid = threadIdx.x, lane = tid & 63, wid = tid >> 6;
  const float4 wv = *(const float4*)(w + lane * 4);
  const float4 bv = *(const float4*)(b + lane * 4);
#pragma unroll
  for (int rr = 0; rr < ROWS / 4; ++rr) {
    const int rl = wid * (ROWS / 4) + rr;
    const size_t o = (size_t)(row0 + rl) * 256 + lane * 4;
    const float4 v = *(const float4*)(x + o);
    float s = v.x + v.y + v.z + v.w;
#pragma unroll
    for (int m = 1; m < 64; m <<= 1) s += __shfl_xor(s, m);
    const float mean = s * (1.f / 256.f);
    const float d0 = v.x - mean, d1 = v.y - mean, d2 = v.z - mean, d3 = v.w - mean;
    float ss = d0 * d0 + d1 * d1 + d2 * d2 + d3 * d3;
#pragma unroll
    for (int m = 1; m < 64; m <<= 1) ss += __shfl_xor(ss, m);
    const float rs = rsqrtf(ss * (1.f / 256.f) + 1e-5f);
    float y0 = d0 * rs * wv.x + bv.x;
    float y1 = d1 * rs * wv.y + bv.y;
    float y2 = d2 * rs * wv.z + bv.z;
    float y3 = d3 * rs * wv.w + bv.w;
    if (pos) {
      const float4 pv = *(const float4*)(pos + o);
      y0 += pv.x; y1 += pv.y; y2 += pv.z; y3 += pv.w;
    }
    uint2 pk; pk.x = cvtpk(y0, y1); pk.y = cvtpk(y2, y3);
    const int byte = (rl * 512 + lane * 8) ^ ((rl & 7) << 4);
    *(uint2*)((char*)As + byte) = pk;
  }
}

// 16x128 GEMM loop reading A from full-K swizzled LDS; W staged per k0.
__device__ __forceinline__ void gemm16x128(const u16* As, const u16* __restrict__ W,
                                           u16 (*Ws)[40], f32x4 acc[2])
{
  const int tid = threadIdx.x, lane = tid & 63, wid = tid >> 6;
  const int g = lane >> 4, lr = lane & 15;
  for (int k0 = 0; k0 < 256; k0 += 32) {
    for (int cid = tid; cid < 512; cid += 256) {
      const int r = cid >> 2, cg = (cid & 3) * 8;
      *(uint4*)&Ws[r][cg] = *(const uint4*)(W + (size_t)r * 256 + k0 + cg);
    }
    __syncthreads();
    const int abyte = (lr * 512 + k0 * 2 + g * 16) ^ ((lr & 7) << 4);
    const bf16x8 af = *(const bf16x8*)((const char*)As + abyte);
#pragma unroll
    for (int nt = 0; nt < 2; ++nt) {
      const bf16x8 bfr = *(const bf16x8*)&Ws[wid * 32 + nt * 16 + lr][g * 8];
      acc[nt] = __builtin_amdgcn_mfma_f32_16x16x32_bf16(af, bfr, acc[nt], 0, 0, 0);
    }
    __syncthreads();
  }
}

// ---------------- q-proj fused with LN(tgt)+qpos; out bf16 scaled -------------
__global__ __launch_bounds__(256)
void qproj_kernel(const float* __restrict__ x, const float* __restrict__ lnw,
                  const float* __restrict__ lnb, const float* __restrict__ pos,
                  const u16* __restrict__ W, const float* __restrict__ bias,
                  u16* __restrict__ out, float scale)
{
  __shared__ u16 As[16 * 256];
  __shared__ u16 Ws[128][40];
  const int tid = threadIdx.x, lane = tid & 63, wid = tid >> 6;
  const int g = lane >> 4, lr = lane & 15;
  const int row0 = blockIdx.x * 16, n0 = blockIdx.y * 128;
  ln_stage<16>(x, row0, lnw, lnb, pos, As);
  f32x4 acc[2] = {};
  gemm16x128(As, W + (size_t)n0 * 256, Ws, acc);
#pragma unroll
  for (int nt = 0; nt < 2; ++nt) {
    const int col = n0 + wid * 32 + nt * 16 + lr;
    const float bv = bias[col];
#pragma unroll
    for (int r = 0; r < 4; ++r) {
      const int row = row0 + g * 4 + r;
      out[(size_t)row * 256 + col] = f2b((acc[nt][r] + bv) * scale);
    }
  }
}

// ---------------- sa_in fused: LN(tgt1)(+qpos for qk), N=768 ------------------
__global__ __launch_bounds__(256)
void sain_kernel(const float* __restrict__ x, const float* __restrict__ lnw,
                 const float* __restrict__ lnb, const float* __restrict__ pos,
                 const u16* __restrict__ W, const float* __restrict__ bias,
                 float* __restrict__ qkb, float* __restrict__ vsb)
{
  __shared__ u16 As[16 * 256];
  __shared__ u16 Ws[128][40];
  const int tid = threadIdx.x, lane = tid & 63, wid = tid >> 6;
  const int g = lane >> 4, lr = lane & 15;
  const int row0 = blockIdx.x * 16, y = blockIdx.y;
  ln_stage<16>(x, row0, lnw, lnb, (y < 4) ? pos : nullptr, As);
  f32x4 acc[2] = {};
  gemm16x128(As, W + (size_t)y * 128 * 256, Ws, acc);
#pragma unroll
  for (int nt = 0; nt < 2; ++nt) {
    const int cl = wid * 32 + nt * 16 + lr;
    const float bv = bias[y * 128 + cl];
#pragma unroll
    for (int r = 0; r < 4; ++r) {
      const int row = row0 + g * 4 + r;
      const float v = acc[nt][r] + bv;
      if (y < 4) qkb[(size_t)row * 512 + y * 128 + cl] = v;
      else       vsb[(size_t)row * 256 + (y - 4) * 128 + cl] = v;
    }
  }
}

// ---------------- FFN lin1 fused with LN(tgt2); GELU; out bf16 ---------------
__global__ __launch_bounds__(256)
void ffn1_kernel(const float* __restrict__ x, const float* __restrict__ lnw,
                 const float* __restrict__ lnb, const u16* __restrict__ W,
                 const float* __restrict__ bias, u16* __restrict__ out)
{
  __shared__ u16 As[64 * 256];
  __shared__ u16 Ws[256][40];
  const int tid = threadIdx.x, lane = tid & 63, wid = tid >> 6;
  const int g = lane >> 4, lr = lane & 15;
  const int row0 = blockIdx.x * 64, n0 = blockIdx.y * 256;
  ln_stage<64>(x, row0, lnw, lnb, nullptr, As);
  f32x4 acc[16] = {};
  for (int k0 = 0; k0 < 256; k0 += 32) {
    for (int cid = tid; cid < 1024; cid += 256) {
      const int r = cid >> 2, cg = (cid & 3) * 8;
      *(uint4*)&Ws[r][cg] = *(const uint4*)(W + (size_t)(n0 + r) * 256 + k0 + cg);
    }
    __syncthreads();
    const int arow = wid * 16 + lr;
    const int abyte = (arow * 512 + k0 * 2 + g * 16) ^ ((arow & 7) << 4);
    const bf16x8 af = *(const bf16x8*)((const char*)As + abyte);
#pragma unroll
    for (int nt = 0; nt < 16; ++nt) {
      const bf16x8 bfr = *(const bf16x8*)&Ws[nt * 16 + lr][g * 8];
      acc[nt] = __builtin_amdgcn_mfma_f32_16x16x32_bf16(af, bfr, acc[nt], 0, 0, 0);
    }
    __syncthreads();
  }
#pragma unroll
  for (int nt = 0; nt < 16; ++nt) {
    const int col = n0 + nt * 16 + lr;
    const float bv = bias[col];
#pragma unroll
    for (int r = 0; r < 4; ++r) {
      const int row = row0 + wid * 16 + g * 4 + r;
      float v = acc[nt][r] + bv;
      v = 0.5f * v * (1.f + erff(v * 0.70710678118654752f));
      out[(size_t)row * 2048 + col] = f2b(v);
    }
  }
}

// ---------------- Generic GEMM: C[M,N] = A[M,K] @ W[N,K]^T + bias -------------
template<int BM, int BN, int WM, int WN, int GELU_, int RES_, int OF32, int OBF>
__global__ __launch_bounds__(256)
void gemm_kernel(const u16* __restrict__ Ap, const u16* __restrict__ W,
                 const float* __restrict__ bias, const float* __restrict__ res,
                 float* __restrict__ Cf, u16* __restrict__ Cb,
                 int M, int N, int K, float scale)
{
  constexpr int WROWS = BM / WM;
  constexpr int WCOLS = BN / WN;
  constexpr int MT = WROWS / 16;
  constexpr int NT = WCOLS / 16;
  static_assert(WM * WN == 4, "4 waves");
  __shared__ u16 As[BM][40];
  __shared__ u16 Ws[BN][40];
  const int tid = threadIdx.x, lane = tid & 63, wid = tid >> 6;
  const int g = lane >> 4, lr = lane & 15;
  const int m0 = blockIdx.x * BM, n0 = blockIdx.y * BN;
  const int wm = wid / WN, wn = wid % WN;
  f32x4 acc[MT][NT] = {};
  for (int k0 = 0; k0 < K; k0 += 32) {
    for (int cid = tid; cid < BM * 4; cid += 256) {
      int r = cid >> 2, cg = (cid & 3) * 8;
      *(uint4*)&As[r][cg] = *(const uint4*)(Ap + (size_t)(m0 + r) * K + k0 + cg);
    }
    for (int cid = tid; cid < BN * 4; cid += 256) {
      int r = cid >> 2, cg = (cid & 3) * 8;
      *(uint4*)&Ws[r][cg] = *(const uint4*)(W + (size_t)(n0 + r) * K + k0 + cg);
    }
    __syncthreads();
    bf16x8 af[MT], bfr[NT];
#pragma unroll
    for (int mt = 0; mt < MT; ++mt) af[mt] = *(const bf16x8*)&As[wm * WROWS + mt * 16 + lr][g * 8];
#pragma unroll
    for (int nt = 0; nt < NT; ++nt) bfr[nt] = *(const bf16x8*)&Ws[wn * WCOLS + nt * 16 + lr][g * 8];
#pragma unroll
    for (int mt = 0; mt < MT; ++mt)
#pragma unroll
      for (int nt = 0; nt < NT; ++nt)
        acc[mt][nt] = __builtin_amdgcn_mfma_f32_16x16x32_bf16(af[mt], bfr[nt], acc[mt][nt], 0, 0, 0);
    __syncthreads();
  }
#pragma unroll
  for (int mt = 0; mt < MT; ++mt)
#pragma unroll
    for (int nt = 0; nt < NT; ++nt) {
      const int col = n0 + wn * WCOLS + nt * 16 + lr;
      const float bv = bias[col];
#pragma unroll
      for (int r = 0; r < 4; ++r) {
        const int row = m0 + wm * WROWS + mt * 16 + g * 4 + r;
        float v = (acc[mt][nt][r] + bv) * scale;
        if constexpr (GELU_) v = 0.5f * v * (1.f + erff(v * 0.70710678118654752f));
        if constexpr (RES_) v += res[(size_t)row * N + col];
        if constexpr (OF32) Cf[(size_t)row * N + col] = v;
        if constexpr (OBF) Cb[(size_t)row * N + col] = f2b(v);
      }
    }
}

// ---------------- KV projection GEMM — BM=64, 3-barrier epilogue --------------
// V permutation within each 32-m block matches the swapped-QK PV k-slot order.
__global__ __launch_bounds__(512, 4)
void kv_gemm_kernel(const float* __restrict__ A, const u16* __restrict__ Wf,
                    const float* __restrict__ biasKV,
                    u16* __restrict__ Kb, u16* __restrict__ Vt)
{
  __shared__ u16 As[64 * 256];
  __shared__ u16 Vs[256 * 64];
  const int tid = threadIdx.x, lane = tid & 63, wid = tid >> 6;
  const int g = lane >> 4, lr = lane & 15;
  const int bidx = blockIdx.x / 85, t = blockIdx.x - bidx * 85;
  const int row0 = blockIdx.x * 64;

  for (int ch = tid; ch < 2048; ch += 512) {
    const int r = ch >> 5, c8 = (ch & 31) * 8;
    const float* ap = A + (size_t)(row0 + r) * 256 + c8;
    const float4 f0 = *(const float4*)ap;
    const float4 f1 = *(const float4*)(ap + 4);
    uint4 pk;
    pk.x = cvtpk(f0.x, f0.y);
    pk.y = cvtpk(f0.z, f0.w);
    pk.z = cvtpk(f1.x, f1.y);
    pk.w = cvtpk(f1.z, f1.w);
    const int byte = r * 512 + c8 * 2;
    *(uint4*)((char*)As + (byte ^ ((r & 7) << 4))) = pk;
  }
  __syncthreads();

  const u16* wbase = Wf + (size_t)wid * 8 * 4 * 512 + lane * 8;
  f32x4 acc[4][4] = {};
#pragma unroll 2
  for (int ks = 0; ks < 8; ++ks) {
    bf16x8 bfv[4], af[4];
#pragma unroll
    for (int nt = 0; nt < 4; ++nt)
      bfv[nt] = *(const bf16x8*)(wbase + (ks * 4 + nt) * 512);
#pragma unroll
    for (int mt = 0; mt < 4; ++mt) {
      const int r = mt * 16 + lr;
      const int byte = r * 512 + ks * 64 + g * 16;
      af[mt] = *(const bf16x8*)((const char*)As + (byte ^ ((r & 7) << 4)));
    }
#pragma unroll
    for (int mt = 0; mt < 4; ++mt)
#pragma unroll
      for (int nt = 0; nt < 4; ++nt)
        acc[mt][nt] = __builtin_amdgcn_mfma_f32_16x16x32_bf16(af[mt], bfv[nt], acc[mt][nt], 0, 0, 0);
  }

  const int isV = wid >> 2;
  if (isV) {
#pragma unroll
    for (int nt = 0; nt < 4; ++nt) {
      const int col = (wid - 4) * 64 + nt * 16 + lr;
      const float bv = biasKV[256 + col];
#pragma unroll
      for (int mt = 0; mt < 4; ++mt) {
        const int slot = (mt >> 1) * 32 + 16 * (mt & 1) + 8 * (g & 1) + 4 * (g >> 1);
#pragma unroll
        for (int r = 0; r < 4; r += 2) {
          const u32 val = cvtpk(acc[mt][nt][r] + bv, acc[mt][nt][r + 1] + bv);
          const int byte = (col * 128 + (slot + r) * 2) ^ ((col & 7) << 4);
          *(u32*)((char*)Vs + byte) = val;
        }
      }
    }
  }
  __syncthreads();

  if (!isV) {
#pragma unroll
    for (int nt = 0; nt < 4; ++nt) {
      const int col = wid * 64 + nt * 16 + lr;
      const float bv = biasKV[col];
#pragma unroll
      for (int mt = 0; mt < 4; ++mt)
#pragma unroll
        for (int r = 0; r < 4; r += 2) {
          const u32 pk = cvtpk(acc[mt][nt][r] + bv, acc[mt][nt][r + 1] + bv);
          const int rowA = mt * 16 + g * 4 + r;
          const int rowB = rowA + 1;
          *(u16*)((char*)As + ((rowA * 512 + col * 2) ^ ((rowA & 7) << 4))) = (u16)pk;
          *(u16*)((char*)As + ((rowB * 512 + col * 2) ^ ((rowB & 7) << 4))) = (u16)(pk >> 16);
        }
    }
  } else {
    const size_t vbase = (size_t)bidx * 256 * 5440 + (size_t)t * 64;
    const int t2 = tid - 256;
#pragma unroll
    for (int p = 0; p < 8; ++p) {
      const int idx = p * 256 + t2;
      const int col = idx >> 3, chunk = idx & 7;
      const int lbyte = col * 128 + ((chunk * 16) ^ ((col & 7) << 4));
      const uint4 v = *(const uint4*)((const char*)Vs + lbyte);
      *(uint4*)(Vt + vbase + (size_t)col * 5440 + chunk * 8) = v;
    }
  }
  __syncthreads();
#pragma unroll
  for (int p = 0; p < 4; ++p) {
    const int idx = p * 512 + tid;
    const int row = idx >> 5, c16 = idx & 31;
    const int lbyte = row * 512 + ((c16 * 16) ^ ((row & 7) << 4));
    const uint4 v = *(const uint4*)((const char*)As + lbyte);
    *(uint4*)(Kb + (size_t)(row0 + row) * 256 + c16 * 8) = v;
  }
}

// ---------------- Cross-attention: swapped-QK 32x32, 1 head/block, 1 qb/wave --
// grid (NCH, 16, 8): blockIdx.z = head; wave wid = qb. Lane holds col q=qb*32+
// (lane&31), 16 m-rows in regs (m=(reg&3)+8*(reg>>2)+4*(lane>>5)). All 4 waves
// share this head's K/V lines (L1/L2 reuse). No LDS.
__global__ __launch_bounds__(256, 4)
void cross_attn_kernel(const u16* __restrict__ Q, const u16* __restrict__ Kb,
                       const u16* __restrict__ Vt, const uint4* __restrict__ biasT5,
                       u32* __restrict__ Opp, float* __restrict__ ML)
{
  const int tid = threadIdx.x, lane = tid & 63, qb = tid >> 6;
  const int ql = lane & 31, hh = lane >> 5;
  const int b = blockIdx.y, c = blockIdx.x;
  const int head = blockIdx.z;
  const int m_base = c * (5440 / NCH);
  const int q = qb * 32 + ql;

  bf16x8 qf0 = zero8(), qf1 = zero8();
  if (q < 100) {
    const u16* qp = &Q[(size_t)(b * 100 + q) * 256 + head * 32 + hh * 8];
    qf0 = *(const bf16x8*)qp;
    qf1 = *(const bf16x8*)(qp + 16);
  }
  float M = -1e30f, L = 0.f;
  f32x16 O;
#pragma unroll
  for (int i = 0; i < 16; ++i) O[i] = 0.f;

  for (int s = 0; s < NSTEP; ++s) {
    const int m0 = m_base + s * 32;
    const u16* kp = &Kb[(size_t)(b * 5440 + m0 + ql) * 256 + head * 32 + hh * 8];
    const bf16x8 kf0 = *(const bf16x8*)kp;
    const bf16x8 kf1 = *(const bf16x8*)(kp + 16);
    const u16* vp = &Vt[((size_t)(b * 8 + head) * 32 + ql) * 5440 + m0 + hh * 8];
    const bf16x8 vf0 = *(const bf16x8*)vp;
    const bf16x8 vf1 = *(const bf16x8*)(vp + 16);
    const uint4* bb = biasT5 + ((size_t)((b * 170 + c * NSTEP + s) * 4 + qb)) * 128 + lane;
    const uint4 b0 = bb[0];
    const uint4 b1 = bb[64];
    f32x16 Sv = {};
    __builtin_amdgcn_s_setprio(1);
    Sv = __builtin_amdgcn_mfma_f32_32x32x16_bf16(kf0, qf0, Sv, 0, 0, 0);
    Sv = __builtin_amdgcn_mfma_f32_32x32x16_bf16(kf1, qf1, Sv, 0, 0, 0);
    __builtin_amdgcn_s_setprio(0);
    const u32 bw[8] = {b0.x, b0.y, b0.z, b0.w, b1.x, b1.y, b1.z, b1.w};
#pragma unroll
    for (int i = 0; i < 8; ++i) {
      Sv[2 * i]     += b2f((u16)bw[i]);
      Sv[2 * i + 1] += b2f((u16)(bw[i] >> 16));
    }
    // max over 16 in-lane (tree) + partner half
    float t8[8];
#pragma unroll
    for (int i = 0; i < 8; ++i) t8[i] = fmaxf(Sv[2 * i], Sv[2 * i + 1]);
    float t4a = fmaxf(fmaxf(t8[0], t8[1]), fmaxf(t8[2], t8[3]));
    float t4b = fmaxf(fmaxf(t8[4], t8[5]), fmaxf(t8[6], t8[7]));
    float mx = fmaxf(t4a, t4b);
    mx = fmaxf(mx, __shfl_xor(mx, 32));
    const float newM = fmaxf(M, mx);
    const float al = __expf(M - newM);
    M = newM;
    float p[16];
#pragma unroll
    for (int i = 0; i < 16; ++i) p[i] = __expf(Sv[i] - newM);
    float s8[8];
#pragma unroll
    for (int i = 0; i < 8; ++i) s8[i] = p[2 * i] + p[2 * i + 1];
    const float sum = ((s8[0] + s8[1]) + (s8[2] + s8[3])) + ((s8[4] + s8[5]) + (s8[6] + s8[7]));
    L = L * al + sum;
#pragma unroll
    for (int i = 0; i < 16; ++i) O[i] *= al;
    union { uint4 u; bf16x8 v; } pb0, pb1;
    pb0.u.x = cvtpk(p[0], p[1]);   pb0.u.y = cvtpk(p[2], p[3]);
    pb0.u.z = cvtpk(p[4], p[5]);   pb0.u.w = cvtpk(p[6], p[7]);
    pb1.u.x = cvtpk(p[8], p[9]);   pb1.u.y = cvtpk(p[10], p[11]);
    pb1.u.z = cvtpk(p[12], p[13]); pb1.u.w = cvtpk(p[14], p[15]);
    __builtin_amdgcn_s_setprio(1);
    O = __builtin_amdgcn_mfma_f32_32x32x16_bf16(vf0, pb0.v, O, 0, 0, 0);
    O = __builtin_amdgcn_mfma_f32_32x32x16_bf16(vf1, pb1.v, O, 0, 0, 0);
    __builtin_amdgcn_s_setprio(0);
  }
  const int bh = b * 8 + head;
  const float Lt = L + __shfl_xor(L, 32);
  if (q < 100) {
    const size_t rb = (size_t)(bh * NCH + c) * 128 + q;
#pragma unroll
    for (int i = 0; i < 8; ++i)
      Opp[rb * 16 + hh * 8 + i] = cvtpk(O[2 * i], O[2 * i + 1]);
    if (hh == 0) { ML[rb * 2] = M; ML[rb * 2 + 1] = Lt; }
  }
}

// ---------------- Combine cross-attn partials -> attn_out bf16 [1600,256] ------
// decode: output d -> reg = (d&3)+4*(d>>3), hh = (d>>2)&1, slot = hh*8+(reg>>1)
__global__ __launch_bounds__(256)
void reduce_attn_kernel(const u32* __restrict__ Opp, const float* __restrict__ ML,
                        u16* __restrict__ outb)
{
  const int row = blockIdx.x;            // 0..1599
  const int b = row / 100, q = row % 100;
  const int h = threadIdx.x >> 5, d = threadIdx.x & 31;
  const int bh = b * 8 + h;
  const int reg = (d & 3) + 4 * (d >> 3);
  const int slot = ((d >> 2) & 1) * 8 + (reg >> 1);
  const int half = reg & 1;
  float gm = -1e30f;
  for (int c = 0; c < NCH; ++c) gm = fmaxf(gm, ML[((size_t)(bh * NCH + c) * 128 + q) * 2]);
  float l = 0.f, o = 0.f;
  for (int c = 0; c < NCH; ++c) {
    const size_t rb = (size_t)(bh * NCH + c) * 128 + q;
    const float w = __expf(ML[rb * 2] - gm);
    l += ML[rb * 2 + 1] * w;
    const u32 pv = Opp[rb * 16 + slot];
    o += b2f((u16)(half ? (pv >> 16) : pv)) * w;
  }
  outb[(size_t)row * 256 + h * 32 + d] = f2b(o / l);
}

// ---------------- Self-attention (NQ=100, tiny) ----------------
__global__ __launch_bounds__(128)
void self_attn_kernel(const float* __restrict__ qk, const float* __restrict__ vs,
                      u16* __restrict__ so)
{
  __shared__ u16 kk[100][36];
  __shared__ u16 vv[100][36];
  __shared__ float S[100][101];
  const int b = blockIdx.x >> 3, h = blockIdx.x & 7;
  const int t = threadIdx.x;
  for (int e = t; e < 3200; e += 128) {
    const int r = e >> 5, cq = e & 31;
    kk[r][cq] = f2b(qk[(size_t)(b * 100 + r) * 512 + 256 + h * 32 + cq]);
    vv[r][cq] = f2b(vs[(size_t)(b * 100 + r) * 256 + h * 32 + cq]);
  }
  __syncthreads();
  if (t < 100) {
    float qr_[32];
#pragma unroll
    for (int cq = 0; cq < 32; ++cq) qr_[cq] = qk[(size_t)(b * 100 + t) * 512 + h * 32 + cq];
    for (int m = 0; m < 100; ++m) {
      float dp = 0.f;
#pragma unroll
      for (int cq = 0; cq < 32; ++cq) dp += qr_[cq] * b2f(kk[m][cq]);
      S[t][m] = dp * 0.17677669529663687f;
    }
    float mx = -1e30f;
    for (int m = 0; m < 100; ++m) mx = fmaxf(mx, S[t][m]);
    float sum = 0.f;
    for (int m = 0; m < 100; ++m) { const float p = __expf(S[t][m] - mx); S[t][m] = p; sum += p; }
    const float inv = 1.f / sum;
    float o[32];
#pragma unroll
    for (int cq = 0; cq < 32; ++cq) o[cq] = 0.f;
    for (int m = 0; m < 100; ++m) {
      const float p = S[t][m];
#pragma unroll
      for (int cq = 0; cq < 32; ++cq) o[cq] += p * b2f(vv[m][cq]);
    }
#pragma unroll
    for (int cq = 0; cq < 32; ++cq)
      so[(size_t)(b * 100 + t) * 256 + h * 32 + cq] = f2b(o[cq] * inv);
  }
}

// ---------------- mask_logits: per-b [100,256] @ hr[b][4096,256]^T -------------
__global__ __launch_bounds__(256)
void mask_gemm_kernel(const u16* __restrict__ tm, const float* __restrict__ hr,
                      float* __restrict__ out)
{
  __shared__ u16 As[112][40];
  __shared__ u16 Bs[64][40];
  const int tid = threadIdx.x, lane = tid & 63, wid = tid >> 6;
  const int g = lane >> 4, lr = lane & 15;
  const int b = blockIdx.y, n0 = blockIdx.x * 64;
  f32x4 acc[7] = {};
  for (int k0 = 0; k0 < 256; k0 += 32) {
    for (int cid = tid; cid < 448; cid += 256) {
      const int r = cid >> 2, cg = (cid & 3) * 8;
      uint4 val = {0u, 0u, 0u, 0u};
      if (r < 100) val = *(const uint4*)&tm[(size_t)(b * 100 + r) * 256 + k0 + cg];
      *(uint4*)&As[r][cg] = val;
    }
    {
      const int r = tid >> 2, cg = (tid & 3) * 8;
      const float* hp = hr + (size_t)(b * 4096 + n0 + r) * 256 + k0 + cg;
      float4 f0 = *(const float4*)hp;
      float4 f1 = *(const float4*)(hp + 4);
      uint4 pk;
      pk.x = cvtpk(f0.x, f0.y); pk.y = cvtpk(f0.z, f0.w);
      pk.z = cvtpk(f1.x, f1.y); pk.w = cvtpk(f1.z, f1.w);
      *(uint4*)&Bs[r][cg] = pk;
    }
    __syncthreads();
    const bf16x8 bfr = *(const bf16x8*)&Bs[wid * 16 + lr][g * 8];
#pragma unroll
    for (int mt = 0; mt < 7; ++mt) {
      const bf16x8 af = *(const bf16x8*)&As[mt * 16 + lr][g * 8];
      acc[mt] = __builtin_amdgcn_mfma_f32_16x16x32_bf16(af, bfr, acc[mt], 0, 0, 0);
    }
    __syncthreads();
  }
#pragma unroll
  for (int mt = 0; mt < 7; ++mt)
#pragma unroll
    for (int r = 0; r < 4; ++r) {
      const int qr = mt * 16 + g * 4 + r;
      if (qr < 100)
        out[(size_t)(b * 100 + qr) * 4096 + n0 + wid * 16 + lr] = acc[mt][r];
    }
}

// =======================================================================
extern "C" void kernel_launch(void* const* d_in, const int* in_sizes, int n_in,
                              void* d_out, int out_size, void* d_ws, size_t ws_size,
                              hipStream_t stream)
{
  (void)in_sizes; (void)n_in; (void)out_size; (void)ws_size;
  const float* tgt      = (const float*)d_in[0];
  const float* memory   = (const float*)d_in[1];
  const float* memhr    = (const float*)d_in[2];
  const float* pbias    = (const float*)d_in[3];
  const float* qpos     = (const float*)d_in[4];
  const float* lncw     = (const float*)d_in[5];
  const float* lncb     = (const float*)d_in[6];
  const float* q_w      = (const float*)d_in[7];
  const float* q_b      = (const float*)d_in[8];
  const float* k_w      = (const float*)d_in[9];
  const float* k_b      = (const float*)d_in[10];
  const float* v_w      = (const float*)d_in[11];
  const float* v_b      = (const float*)d_in[12];
  const float* out_w    = (const float*)d_in[13];
  const float* out_b    = (const float*)d_in[14];
  const float* lnsw     = (const float*)d_in[15];
  const float* lnsb     = (const float*)d_in[16];
  const float* sa_in_w  = (const float*)d_in[17];
  const float* sa_in_b  = (const float*)d_in[18];
  const float* sa_out_w = (const float*)d_in[19];
  const float* sa_out_b = (const float*)d_in[20];
  const float* lnfw     = (const float*)d_in[21];
  const float* lnfb     = (const float*)d_in[22];
  const float* l1w      = (const float*)d_in[23];
  const float* l1b      = (const float*)d_in[24];
  const float* l2w      = (const float*)d_in[25];
  const float* l2b      = (const float*)d_in[26];
  const float* me_w     = (const float*)d_in[27];
  const float* me_b     = (const float*)d_in[28];
  float* outf = (float*)d_out;

  char* ws = (char*)d_ws;
  size_t off = 0;
  auto alloc = [&](size_t bytes) -> void* {
    void* p = ws + off;
    off = (off + bytes + 255) & ~(size_t)255;
    return p;
  };
  u16*   Wf    = (u16*)alloc((size_t)131072 * 2);
  u16*   qW    = (u16*)alloc((size_t)65536 * 2);
  u16*   outW  = (u16*)alloc((size_t)65536 * 2);
  u16*   saW   = (u16*)alloc((size_t)196608 * 2);
  u16*   saoW  = (u16*)alloc((size_t)65536 * 2);
  u16*   l1W   = (u16*)alloc((size_t)524288 * 2);
  u16*   l2W   = (u16*)alloc((size_t)524288 * 2);
  u16*   meW   = (u16*)alloc((size_t)65536 * 2);
  float* kvB   = (float*)alloc((size_t)512 * 4);
  uint4* biasT5= (uint4*)alloc((size_t)16 * 170 * 4 * 128 * 16);
  u16*   Qb    = (u16*)alloc((size_t)409600 * 2);
  u16*   Kb    = (u16*)alloc((size_t)22282240 * 2);
  u16*   Vt    = (u16*)alloc((size_t)22282240 * 2);
  u32*   Opp   = (u32*)alloc((size_t)(128 * NCH * 128 * 16) * 4);
  float* MLp   = (float*)alloc((size_t)(128 * NCH * 128 * 2) * 4);
  u16*   attno = (u16*)alloc((size_t)409600 * 2);
  float* tgt1  = (float*)alloc((size_t)409600 * 4);
  float* qkb   = (float*)alloc((size_t)819200 * 4);
  float* vsb   = (float*)alloc((size_t)409600 * 4);
  u16*   sob   = (u16*)alloc((size_t)409600 * 2);
  float* tgt2  = (float*)alloc((size_t)409600 * 4);
  u16*   hb    = (u16*)alloc((size_t)3276800 * 2);
  u16*   t3b   = (u16*)alloc((size_t)409600 * 2);
  u16*   tmb   = (u16*)alloc((size_t)409600 * 2);

  const float SCALE = 0.17677669529663687f;  // 32^-0.5

  // ---- single prep launch ----
  PrepArgs pa;
  pa.seg[0] = {q_w,      qW,   16384};
  pa.seg[1] = {out_w,    outW, 16384};
  pa.seg[2] = {sa_in_w,  saW,  49152};
  pa.seg[3] = {sa_out_w, saoW, 16384};
  pa.seg[4] = {l1w,      l1W,  131072};
  pa.seg[5] = {l2w,      l2W,  131072};
  pa.seg[6] = {me_w,     meW,  16384};
  pa.k_w = k_w; pa.v_w = v_w; pa.k_b = k_b; pa.v_b = v_b; pa.pbias = pbias;
  pa.Wf = Wf; pa.biasT5 = biasT5; pa.kvB = kvB;
  prep_kernel<<<4258, 256, 0, stream>>>(pa);

  // ---- cross attention ----
  qproj_kernel<<<dim3(100, 2), 256, 0, stream>>>(tgt, lncw, lncb, qpos, qW, q_b, Qb, SCALE);
  kv_gemm_kernel<<<dim3(1360), 512, 0, stream>>>(memory, Wf, kvB, Kb, Vt);
  cross_attn_kernel<<<dim3(NCH, 16, 8), 256, 0, stream>>>(Qb, Kb, Vt, biasT5, Opp, MLp);
  reduce_attn_kernel<<<1600, 256, 0, stream>>>(Opp, MLp, attno);
  gemm_kernel<16, 128, 1, 4, 0, 1, 1, 0><<<dim3(100, 2), 256, 0, stream>>>(
      attno, outW, out_b, tgt, tgt1, nullptr, 1600, 256, 256, 1.f);

  // ---- self attention ----
  sain_kernel<<<dim3(100, 6), 256, 0, stream>>>(tgt1, lnsw, lnsb, qpos, saW, sa_in_b, qkb, vsb);
  self_attn_kernel<<<128, 128, 0, stream>>>(qkb, vsb, sob);
  gemm_kernel<16, 128, 1, 4, 0, 1, 1, 0><<<dim3(100, 2), 256, 0, stream>>>(
      sob, saoW, sa_out_b, tgt1, tgt2, nullptr, 1600, 256, 256, 1.f);

  // ---- FFN ----
  ffn1_kernel<<<dim3(25, 8), 256, 0, stream>>>(tgt2, lnfw, lnfb, l1W, l1b, hb);
  gemm_kernel<16, 128, 1, 4, 0, 1, 1, 1><<<dim3(100, 2), 256, 0, stream>>>(
      hb, l2W, l2b, tgt2, outf, t3b, 1600, 256, 2048, 1.f);

  // ---- mask branch ----
  gemm_kernel<16, 128, 1, 4, 0, 0, 0, 1><<<dim3(100, 2), 256, 0, stream>>>(
      t3b, meW, me_b, nullptr, nullptr, tmb, 1600, 256, 256, 1.f);
  mask_gemm_kernel<<<dim3(64, 16), 256, 0, stream>>>(tmb, memhr, outf + 409600);
}